// Round 1
// 1149.687 us; speedup vs baseline: 1.6110x; 1.6110x over previous
//
#include <hip/hip_runtime.h>

// WindowAttention (Swin-style), MI355X. Round 5: kill LDS bank conflicts.
// rocprof r4: k_gemm_qkv 886us, SQ_LDS_BANK_CONFLICT=3.58e8 (~66% of cycles),
// MfmaUtil 12%. Fixes:
//  - fragment-contiguous LDS layout [hi/lo][kq][128][8] -> wave b128 ops are
//    contiguous 1KB (zero conflicts), replaces stride-40 padded rows
//  - weights pre-split ONCE (k_prep_w) into per-(nb,kc) LDS-image order,
//    staged via global_load_lds width=16 (zero VALU, zero conflicts)
//  - K2: K stored transposed kt[32][53] (pad 53 -> conflict-free; old layout
//    was a 49-way same-bank read per fmaf), softmax wave-parallelized
//    (4 lanes/row + shfl_xor instead of 49 serial lanes)
// ws layout: [qkv slots 231.2MB][Bfrag 1.77MB][Pfrag 0.59MB] = 233.6MB.
// Fallback: round-0 fp32 kernels if ws too small.

#define DIMC   384
#define NTOK   49
#define NHEAD  12
#define HD     32
#define NWIN   64
#define BWIN   2048
#define SCALE  0.17677669529663687f  // 1/sqrt(32)

#define SLOT     4704                // ushorts per (b,h): 3*49*32
#define NBQ      9
#define NBP      3
#define FRAG_BLK 8192                // ushorts per (nb,kc): [2 hl][4 kq][128][8]

#define WS_SLOTS ((size_t)BWIN * NHEAD * SLOT)      // ushorts
#define WS_BFRAG ((size_t)NBQ * 12 * FRAG_BLK)
#define WS_PFRAG ((size_t)NBP * 12 * FRAG_BLK)
#define WS_NEED  ((WS_SLOTS + WS_BFRAG + WS_PFRAG) * 2)   // bytes

typedef short bf16x8 __attribute__((ext_vector_type(8)));
typedef unsigned short u16x8 __attribute__((ext_vector_type(8)));
typedef float f32x4  __attribute__((ext_vector_type(4)));

__device__ __forceinline__ unsigned short f2bf(float f) {
    union { float f; unsigned u; } v; v.f = f;
    unsigned r = v.u + 0x7fffu + ((v.u >> 16) & 1u);   // RTN-even
    return (unsigned short)(r >> 16);
}
__device__ __forceinline__ float bf2f(unsigned short h) {
    union { unsigned u; float f; } v; v.u = ((unsigned)h) << 16;
    return v.f;
}
__device__ __forceinline__ void split2(float x, unsigned short& hi, unsigned short& lo) {
    hi = f2bf(x);
    lo = f2bf(x - bf2f(hi));
}
__device__ __forceinline__ float4 ld4(const float* p) {
    return *reinterpret_cast<const float4*>(p);
}
// async global->LDS, 16B/lane. LDS dest = wave-uniform base + lane*16.
__device__ __forceinline__ void gload16(const unsigned short* g, unsigned short* l) {
    __builtin_amdgcn_global_load_lds(
        (const __attribute__((address_space(1))) void*)g,
        (__attribute__((address_space(3))) void*)l, 16, 0, 0);
}

// ---------------------------------------------------------------------------
// K0: pre-split a [384 x ncols] fp32 weight into hi/lo bf16 fragment blocks:
// dst[(nb*12+kc)*8192 + {hi:0,lo:4096} + (kq*128+rl)*8 + e] = w[(kc*32+kq*8+e)*ncols + nb*128+rl]
// One thread per 8-elem fragment. ncols = 1152 (qkv) or 384 (proj).
// ---------------------------------------------------------------------------
__global__ __launch_bounds__(256) void k_prep_w(
    const float* __restrict__ w, unsigned short* __restrict__ dst, int ncols)
{
    int f = blockIdx.x * 256 + threadIdx.x;
    if (f >= ncols * 48) return;
    int nb = f / 6144, rem = f - nb * 6144;     // 6144 = 12*4*128
    int kc = rem >> 9, rem2 = rem & 511;
    int kq = rem2 >> 7, rl = rem2 & 127;
    int n = nb * 128 + rl, k0 = kc * 32 + kq * 8;
    u16x8 h8, l8;
    #pragma unroll
    for (int e = 0; e < 8; ++e) {
        unsigned short hh, ll;
        split2(w[(size_t)(k0 + e) * ncols + n], hh, ll);
        h8[e] = hh; l8[e] = ll;
    }
    size_t base = ((size_t)(nb * 12 + kc) << 13) + (size_t)((kq << 7) + rl) * 8;
    *reinterpret_cast<u16x8*>(&dst[base])        = h8;
    *reinterpret_cast<u16x8*>(&dst[base + 4096]) = l8;
}

// ---------------------------------------------------------------------------
// K1: Y = X(100352x384) @ W(384x1152) + b, split-bf16 3-term MFMA,
// out bf16 to ws slots. Grid (784,9), block 256 (4 waves, 2x2).
// LDS: Als/Bls [2 hl][4 kq][128][8] ushorts (16KB each) -> all wave b128
// reads/writes contiguous 1KB, conflict-free. B via global_load_lds.
// ---------------------------------------------------------------------------
__global__ __launch_bounds__(256) void k_gemm_qkv(
    const float* __restrict__ x, const unsigned short* __restrict__ Bfrag,
    const float* __restrict__ qb, unsigned short* __restrict__ ws)
{
    __shared__ __align__(16) unsigned short Als[FRAG_BLK];
    __shared__ __align__(16) unsigned short Bls[FRAG_BLK];

    const int t = threadIdx.x;
    const int wave = t >> 6, l = t & 63, lj = l & 15, quad = l >> 4;
    const int wm = wave & 1, wn = wave >> 1;
    const int gm0 = blockIdx.x * 128, gn0 = blockIdx.y * 128;

    // two A fragments per thread: fs = kq*128 + rl
    const int fs0 = t, fs1 = t + 256;
    const float* xp0 = x + (size_t)(gm0 + (fs0 & 127)) * DIMC + (fs0 >> 7) * 8;
    const float* xp1 = x + (size_t)(gm0 + (fs1 & 127)) * DIMC + (fs1 >> 7) * 8;
    const unsigned short* Bg = Bfrag + (size_t)blockIdx.y * 12 * FRAG_BLK;

    f32x4 acc[4][4];
    #pragma unroll
    for (int i = 0; i < 4; ++i)
        #pragma unroll
        for (int j = 0; j < 4; ++j) acc[i][j] = (f32x4)0.0f;

    for (int kc = 0; kc < 12; ++kc) {
        // B: 16 x 1KB async chunks, 4 per wave (L2-resident source)
        #pragma unroll
        for (int c = 0; c < 4; ++c) {
            int ch = wave * 4 + c;
            gload16(Bg + (size_t)kc * FRAG_BLK + ch * 512 + l * 8, &Bls[ch * 512]);
        }
        // A: fp32 -> hi/lo split in regs, contiguous 16B LDS writes
        {
            float4 x0 = ld4(xp0 + kc * 32), x1 = ld4(xp0 + kc * 32 + 4);
            u16x8 h8, l8; unsigned short hh, ll;
            split2(x0.x, hh, ll); h8[0] = hh; l8[0] = ll;
            split2(x0.y, hh, ll); h8[1] = hh; l8[1] = ll;
            split2(x0.z, hh, ll); h8[2] = hh; l8[2] = ll;
            split2(x0.w, hh, ll); h8[3] = hh; l8[3] = ll;
            split2(x1.x, hh, ll); h8[4] = hh; l8[4] = ll;
            split2(x1.y, hh, ll); h8[5] = hh; l8[5] = ll;
            split2(x1.z, hh, ll); h8[6] = hh; l8[6] = ll;
            split2(x1.w, hh, ll); h8[7] = hh; l8[7] = ll;
            *reinterpret_cast<u16x8*>(&Als[fs0 * 8])        = h8;
            *reinterpret_cast<u16x8*>(&Als[4096 + fs0 * 8]) = l8;
        }
        {
            float4 x0 = ld4(xp1 + kc * 32), x1 = ld4(xp1 + kc * 32 + 4);
            u16x8 h8, l8; unsigned short hh, ll;
            split2(x0.x, hh, ll); h8[0] = hh; l8[0] = ll;
            split2(x0.y, hh, ll); h8[1] = hh; l8[1] = ll;
            split2(x0.z, hh, ll); h8[2] = hh; l8[2] = ll;
            split2(x0.w, hh, ll); h8[3] = hh; l8[3] = ll;
            split2(x1.x, hh, ll); h8[4] = hh; l8[4] = ll;
            split2(x1.y, hh, ll); h8[5] = hh; l8[5] = ll;
            split2(x1.z, hh, ll); h8[6] = hh; l8[6] = ll;
            split2(x1.w, hh, ll); h8[7] = hh; l8[7] = ll;
            *reinterpret_cast<u16x8*>(&Als[fs1 * 8])        = h8;
            *reinterpret_cast<u16x8*>(&Als[4096 + fs1 * 8]) = l8;
        }
        __syncthreads();

        bf16x8 ah[4], al[4], bh[4], bl[4];
        #pragma unroll
        for (int i = 0; i < 4; ++i) {
            int ra = (quad * 128 + wm * 64 + i * 16 + lj) * 8;
            ah[i] = *reinterpret_cast<const bf16x8*>(&Als[ra]);
            al[i] = *reinterpret_cast<const bf16x8*>(&Als[4096 + ra]);
            int rb = (quad * 128 + wn * 64 + i * 16 + lj) * 8;
            bh[i] = *reinterpret_cast<const bf16x8*>(&Bls[rb]);
            bl[i] = *reinterpret_cast<const bf16x8*>(&Bls[4096 + rb]);
        }
        #pragma unroll
        for (int tm = 0; tm < 4; ++tm)
            #pragma unroll
            for (int tn = 0; tn < 4; ++tn) {
                acc[tm][tn] = __builtin_amdgcn_mfma_f32_16x16x32_bf16(ah[tm], bh[tn], acc[tm][tn], 0, 0, 0);
                acc[tm][tn] = __builtin_amdgcn_mfma_f32_16x16x32_bf16(ah[tm], bl[tn], acc[tm][tn], 0, 0, 0);
                acc[tm][tn] = __builtin_amdgcn_mfma_f32_16x16x32_bf16(al[tm], bh[tn], acc[tm][tn], 0, 0, 0);
            }
        __syncthreads();
    }

    // epilogue: +bias, bf16, scatter into (b,h,part) slots
    #pragma unroll
    for (int tn = 0; tn < 4; ++tn) {
        int col = gn0 + wn * 64 + tn * 16 + lj;          // 0..1151
        float bias = qb[col];
        int part = col / 384, rem = col - part * 384;
        int h = rem >> 5, d = rem & 31;
        #pragma unroll
        for (int tm = 0; tm < 4; ++tm) {
            #pragma unroll
            for (int rr = 0; rr < 4; ++rr) {
                int row = gm0 + wm * 64 + tm * 16 + quad * 4 + rr;
                int b = row / 49, n = row - b * 49;
                size_t off = ((size_t)(b * NHEAD + h) * 3 + part) * 1568 + n * HD + d;
                ws[off] = f2bf(acc[tm][tn][rr] + bias);
            }
        }
    }
}

// ---------------------------------------------------------------------------
// K2: per-(b,h) attention. K stored TRANSPOSED kt[32][53] (pad 53 ->
// conflict-free transpose-writes and QK reads: gcd(21,32)=1).
// QK mapped (i = o>>6, j = o&63): q broadcast, kt stride-1 over lanes.
// Softmax: 4 lanes/row + shfl_xor reduce. PV unchanged (was conflict-free).
// ---------------------------------------------------------------------------
__global__ __launch_bounds__(256) void k_attn_scalar(
    unsigned short* __restrict__ ws, const float* __restrict__ mask,
    const float* __restrict__ bias_table, const int* __restrict__ rel_idx)
{
    __shared__ float qf[NTOK * HD];     // 6.3 KB
    __shared__ float kt[32 * 53];       // 6.8 KB transposed
    __shared__ float vf[NTOK * HD];     // 6.3 KB
    __shared__ float sf[NTOK * 52];     // 10.2 KB

    const int t = threadIdx.x, bx = blockIdx.x;    // bx = b*12 + h
    const int b = bx / NHEAD, h = bx - b * NHEAD;
    unsigned short* qp = ws + (size_t)bx * SLOT;

    for (int i = t; i < NTOK * HD; i += 256) {
        qf[i] = bf2f(qp[i]);
        int j = i >> 5, d = i & 31;
        kt[d * 53 + j] = bf2f(qp[1568 + i]);
        vf[i] = bf2f(qp[3136 + i]);
    }
    __syncthreads();

    const int mb = (b & (NWIN - 1)) * NTOK * NTOK;
    for (int p = 0; p < 13; ++p) {                 // 49 rows x 64 padded cols
        int o = p * 256 + t;
        int i = o >> 6, j = o & 63;
        if (i < NTOK && j < NTOK) {
            float a = 0.0f;
            #pragma unroll
            for (int d = 0; d < HD; ++d) a = fmaf(qf[i * HD + d], kt[d * 53 + j], a);
            int o2 = i * NTOK + j;
            sf[i * 52 + j] = a * SCALE + bias_table[rel_idx[o2] * NHEAD + h] + mask[mb + o2];
        }
    }
    __syncthreads();

    {   // wave-parallel softmax: 4 lanes per row
        int r = t >> 2, sub = t & 3;
        if (r < NTOK) {
            float* row = &sf[r * 52];
            float m = -1e30f;
            for (int j = sub; j < NTOK; j += 4) m = fmaxf(m, row[j]);
            m = fmaxf(m, __shfl_xor(m, 1));
            m = fmaxf(m, __shfl_xor(m, 2));
            float s = 0.0f;
            for (int j = sub; j < NTOK; j += 4) { float e = __expf(row[j] - m); row[j] = e; s += e; }
            s += __shfl_xor(s, 1);
            s += __shfl_xor(s, 2);
            float inv = 1.0f / s;
            for (int j = sub; j < NTOK; j += 4) row[j] *= inv;
        }
    }
    __syncthreads();

    for (int o = t; o < NTOK * HD; o += 256) {
        int i = o >> 5, d = o & 31;
        float a = 0.0f;
        #pragma unroll 7
        for (int j = 0; j < NTOK; ++j) a = fmaf(sf[i * 52 + j], vf[j * HD + d], a);
        qp[o] = f2bf(a);   // global write; all global reads finished pre-barrier
    }
}

// ---------------------------------------------------------------------------
// K3: out = Y2(100352x384 bf16 slots) @ proj_w + b, fp32 out. Grid (784,3).
// A gathered from slots via per-lane-source global_load_lds (dest is
// lane-contiguous fragment layout by construction); B from Pfrag. 2-term.
// ---------------------------------------------------------------------------
__global__ __launch_bounds__(256) void k_gemm_proj(
    const unsigned short* __restrict__ ws, const unsigned short* __restrict__ Pfrag,
    const float* __restrict__ pbias, float* __restrict__ out)
{
    __shared__ __align__(16) unsigned short Als[4096];      // [4 kq][128][8], 8KB
    __shared__ __align__(16) unsigned short Bls[FRAG_BLK];  // hi/lo, 16KB

    const int t = threadIdx.x;
    const int wave = t >> 6, l = t & 63, lj = l & 15, quad = l >> 4;
    const int wm = wave & 1, wn = wave >> 1;
    const int gm0 = blockIdx.x * 128, gn0 = blockIdx.y * 128;

    // per-lane A gather bases (kc-invariant): fragment fs = ch*64 + l
    const int ch0 = wave * 2, ch1 = wave * 2 + 1;
    size_t abase0, abase1;
    {
        int fs = ch0 * 64 + l;
        int kq = fs >> 7, rl = fs & 127, row = gm0 + rl;
        int b = row / 49, n = row - b * 49;
        abase0 = (size_t)(b * NHEAD) * SLOT + n * HD + kq * 8;
    }
    {
        int fs = ch1 * 64 + l;
        int kq = fs >> 7, rl = fs & 127, row = gm0 + rl;
        int b = row / 49, n = row - b * 49;
        abase1 = (size_t)(b * NHEAD) * SLOT + n * HD + kq * 8;
    }
    const unsigned short* Bg = Pfrag + (size_t)blockIdx.y * 12 * FRAG_BLK;

    f32x4 acc[4][4];
    #pragma unroll
    for (int i = 0; i < 4; ++i)
        #pragma unroll
        for (int j = 0; j < 4; ++j) acc[i][j] = (f32x4)0.0f;

    for (int kc = 0; kc < 12; ++kc) {       // kc == head index
        #pragma unroll
        for (int c = 0; c < 4; ++c) {
            int ch = wave * 4 + c;
            gload16(Bg + (size_t)kc * FRAG_BLK + ch * 512 + l * 8, &Bls[ch * 512]);
        }
        gload16(ws + abase0 + (size_t)kc * SLOT, &Als[ch0 * 512]);
        gload16(ws + abase1 + (size_t)kc * SLOT, &Als[ch1 * 512]);
        __syncthreads();

        bf16x8 a[4], bh[4], bl[4];
        #pragma unroll
        for (int i = 0; i < 4; ++i) {
            a[i] = *reinterpret_cast<const bf16x8*>(&Als[(quad * 128 + wm * 64 + i * 16 + lj) * 8]);
            int rb = (quad * 128 + wn * 64 + i * 16 + lj) * 8;
            bh[i] = *reinterpret_cast<const bf16x8*>(&Bls[rb]);
            bl[i] = *reinterpret_cast<const bf16x8*>(&Bls[4096 + rb]);
        }
        #pragma unroll
        for (int tm = 0; tm < 4; ++tm)
            #pragma unroll
            for (int tn = 0; tn < 4; ++tn) {
                acc[tm][tn] = __builtin_amdgcn_mfma_f32_16x16x32_bf16(a[tm], bh[tn], acc[tm][tn], 0, 0, 0);
                acc[tm][tn] = __builtin_amdgcn_mfma_f32_16x16x32_bf16(a[tm], bl[tn], acc[tm][tn], 0, 0, 0);
            }
        __syncthreads();
    }

    #pragma unroll
    for (int tn = 0; tn < 4; ++tn) {
        int col = gn0 + wn * 64 + tn * 16 + lj;
        float bias = pbias[col];
        #pragma unroll
        for (int tm = 0; tm < 4; ++tm)
            #pragma unroll
            for (int rr = 0; rr < 4; ++rr) {
                int row = gm0 + wm * 64 + tm * 16 + quad * 4 + rr;
                out[(size_t)row * DIMC + col] = acc[tm][tn][rr] + bias;
            }
    }
}

// ============================ fp32 fallback (round 0) =======================
__global__ __launch_bounds__(192) void k_qkv_attn(
    const float* __restrict__ x, const float* __restrict__ mask,
    const float* __restrict__ qkv_w, const float* __restrict__ qkv_b,
    const float* __restrict__ bias_table, const int* __restrict__ rel_idx,
    float* __restrict__ out)
{
    __shared__ __align__(16) float xs_t[64 * 68];
    __shared__ __align__(16) float qs[NTOK * HD];
    __shared__ __align__(16) float ks_[NTOK * HD];
    __shared__ __align__(16) float vs[NTOK * HD];
    __shared__ __align__(16) union { float w[64 * 96]; float s[NTOK * 56]; } u;

    const int t = threadIdx.x, b = blockIdx.x;
    const int tx = t % 12, ty = t / 12;
    const float* xb = x + (size_t)b * NTOK * DIMC;
    const int mbase = (b % NWIN) * NTOK * NTOK;

    for (int h = 0; h < NHEAD; ++h) {
        float acc[4][8];
        #pragma unroll
        for (int r = 0; r < 4; ++r)
            #pragma unroll
            for (int cc = 0; cc < 8; ++cc) acc[r][cc] = 0.0f;
        for (int c0 = 0; c0 < DIMC; c0 += 64) {
            for (int idx = t; idx < NTOK * 64; idx += 192) {
                int i = idx >> 6, kk2 = idx & 63;
                xs_t[kk2 * 68 + i] = xb[i * DIMC + c0 + kk2];
            }
            for (int idx = t; idx < 64 * 96; idx += 192) {
                int kk2 = idx / 96, c = idx % 96;
                int col = (c >> 5) * DIMC + h * HD + (c & 31);
                u.w[kk2 * 96 + c] = qkv_w[(size_t)(c0 + kk2) * (3 * DIMC) + col];
            }
            __syncthreads();
            #pragma unroll 8
            for (int kk2 = 0; kk2 < 64; ++kk2) {
                const float4 xv = ld4(&xs_t[kk2 * 68 + ty * 4]);
                const float4 w0 = ld4(&u.w[kk2 * 96 + tx * 8]);
                const float4 w1 = ld4(&u.w[kk2 * 96 + tx * 8 + 4]);
                const float xr[4] = {xv.x, xv.y, xv.z, xv.w};
                const float wc[8] = {w0.x, w0.y, w0.z, w0.w, w1.x, w1.y, w1.z, w1.w};
                #pragma unroll
                for (int r = 0; r < 4; ++r)
                    #pragma unroll
                    for (int cc = 0; cc < 8; ++cc)
                        acc[r][cc] = fmaf(xr[r], wc[cc], acc[r][cc]);
            }
            __syncthreads();
        }
        {
            const int part = tx >> 2, cbase = (tx & 3) * 8;
            float* dst = (part == 0) ? qs : (part == 1) ? ks_ : vs;
            #pragma unroll
            for (int r = 0; r < 4; ++r) {
                int i = ty * 4 + r;
                if (i < NTOK)
                    #pragma unroll
                    for (int cc = 0; cc < 8; ++cc) {
                        int c5 = cbase + cc;
                        dst[i * HD + c5] = acc[r][cc] + qkv_b[part * DIMC + h * HD + c5];
                    }
            }
        }
        __syncthreads();
        for (int o = t; o < NTOK * NTOK; o += 192) {
            int i = o / 49, j = o % 49;
            float4 a4 = {0.f, 0.f, 0.f, 0.f};
            #pragma unroll
            for (int seg = 0; seg < 8; ++seg) {
                float4 q4 = ld4(&qs[i * HD + seg * 4]);
                float4 k4 = ld4(&ks_[j * HD + seg * 4]);
                a4.x = fmaf(q4.x, k4.x, a4.x); a4.y = fmaf(q4.y, k4.y, a4.y);
                a4.z = fmaf(q4.z, k4.z, a4.z); a4.w = fmaf(q4.w, k4.w, a4.w);
            }
            u.s[i * 56 + j] = (a4.x + a4.y + a4.z + a4.w) * SCALE
                            + bias_table[rel_idx[o] * NHEAD + h] + mask[mbase + o];
        }
        __syncthreads();
        if (t < NTOK) {
            float* row = &u.s[t * 56];
            float m = row[0];
            for (int j = 1; j < NTOK; ++j) m = fmaxf(m, row[j]);
            float ssum = 0.f;
            for (int j = 0; j < NTOK; ++j) { float e = __expf(row[j] - m); row[j] = e; ssum += e; }
            float inv = 1.0f / ssum;
            for (int j = 0; j < NTOK; ++j) row[j] *= inv;
        }
        __syncthreads();
        for (int o = t; o < NTOK * 8; o += 192) {
            int i = o >> 3, dg = o & 7;
            float4 a = {0.f, 0.f, 0.f, 0.f};
            for (int j = 0; j < NTOK; ++j) {
                float sj = u.s[i * 56 + j];
                float4 v4 = ld4(&vs[j * HD + dg * 4]);
                a.x = fmaf(sj, v4.x, a.x); a.y = fmaf(sj, v4.y, a.y);
                a.z = fmaf(sj, v4.z, a.z); a.w = fmaf(sj, v4.w, a.w);
            }
            *reinterpret_cast<float4*>(&out[(size_t)(b * NTOK + i) * DIMC + h * HD + dg * 4]) = a;
        }
        __syncthreads();
    }
}

__global__ __launch_bounds__(192) void k_proj(
    float* __restrict__ io, const float* __restrict__ proj_w,
    const float* __restrict__ proj_b)
{
    __shared__ __align__(16) float ys_t[DIMC * 20];
    __shared__ __align__(16) float wch[16 * DIMC];
    const int t = threadIdx.x, row0 = blockIdx.x * 16;
    const int tx = t % 48, ty = t / 48;
    for (int idx = t; idx < 16 * DIMC; idx += 192) {
        int i = idx / DIMC, k = idx % DIMC;
        ys_t[k * 20 + i] = io[(size_t)(row0 + i) * DIMC + k];
    }
    float acc[4][8];
    #pragma unroll
    for (int r = 0; r < 4; ++r)
        #pragma unroll
        for (int cc = 0; cc < 8; ++cc) acc[r][cc] = 0.0f;
    for (int k0 = 0; k0 < DIMC; k0 += 16) {
        for (int idx = t; idx < 16 * DIMC; idx += 192) {
            int kk2 = idx / DIMC, c = idx % DIMC;
            wch[kk2 * DIMC + c] = proj_w[(size_t)(k0 + kk2) * DIMC + c];
        }
        __syncthreads();
        #pragma unroll
        for (int kk2 = 0; kk2 < 16; ++kk2) {
            const float4 xv = ld4(&ys_t[(k0 + kk2) * 20 + ty * 4]);
            const float4 w0 = ld4(&wch[kk2 * DIMC + tx * 8]);
            const float4 w1 = ld4(&wch[kk2 * DIMC + tx * 8 + 4]);
            const float xr[4] = {xv.x, xv.y, xv.z, xv.w};
            const float wc[8] = {w0.x, w0.y, w0.z, w0.w, w1.x, w1.y, w1.z, w1.w};
            #pragma unroll
            for (int r = 0; r < 4; ++r)
                #pragma unroll
                for (int cc = 0; cc < 8; ++cc)
                    acc[r][cc] = fmaf(xr[r], wc[cc], acc[r][cc]);
        }
        __syncthreads();
    }
    #pragma unroll
    for (int r = 0; r < 4; ++r) {
        int i = ty * 4 + r;
        float* dst = &io[(size_t)(row0 + i) * DIMC + tx * 8];
        #pragma unroll
        for (int cc = 0; cc < 8; ++cc) dst[cc] = acc[r][cc] + proj_b[tx * 8 + cc];
    }
}

extern "C" void kernel_launch(void* const* d_in, const int* in_sizes, int n_in,
                              void* d_out, int out_size, void* d_ws, size_t ws_size,
                              hipStream_t stream) {
    const float* x          = (const float*)d_in[0];
    const float* mask       = (const float*)d_in[1];
    const float* qkv_w      = (const float*)d_in[2];
    const float* qkv_b      = (const float*)d_in[3];
    const float* proj_w     = (const float*)d_in[4];
    const float* proj_b     = (const float*)d_in[5];
    const float* bias_table = (const float*)d_in[6];
    const int*   rel_idx    = (const int*)d_in[7];
    float* out = (float*)d_out;

    if (ws_size >= WS_NEED) {
        unsigned short* ws = (unsigned short*)d_ws;
        unsigned short* Bf = ws + WS_SLOTS;
        unsigned short* Pf = Bf + WS_BFRAG;
        k_prep_w<<<216, 256, 0, stream>>>(qkv_w, Bf, 3 * DIMC);   // 55296 frags
        k_prep_w<<<72, 256, 0, stream>>>(proj_w, Pf, DIMC);       // 18432 frags
        dim3 g1(784, 9);
        k_gemm_qkv<<<g1, 256, 0, stream>>>(x, Bf, qkv_b, ws);
        k_attn_scalar<<<BWIN * NHEAD, 256, 0, stream>>>(ws, mask, bias_table, rel_idx);
        dim3 g3(784, 3);
        k_gemm_proj<<<g3, 256, 0, stream>>>(ws, Pf, proj_b, out);
    } else {
        k_qkv_attn<<<BWIN, 192, 0, stream>>>(x, mask, qkv_w, qkv_b,
                                             bias_table, rel_idx, out);
        k_proj<<<(BWIN * NTOK) / 16, 192, 0, stream>>>(out, proj_w, proj_b);
    }
}

// Round 3
// 824.944 us; speedup vs baseline: 2.2452x; 1.3937x over previous
//
#include <hip/hip_runtime.h>

// WindowAttention (Swin-style), MI355X. Round 6 resubmit (r6 bench hit
// GPUAcquisitionTimeout — no counters; kernel unchanged): MFMA attention.
// rocprof r5: k_attn_scalar 524us = 46% of total, MfmaUtil 0, VALUBusy 45%,
// HBM 4.7% -> LDS-issue-rate bound scalar matmuls on the wrong pipe.
// K2 rewritten as per-wave MFMA tile (pad 49->64):
//  - Q/K frags global->reg direct (slot layout IS frag layout), predicated
//  - bias+mask precomputed into comb[w][h][49][64] fp32 (k_prep_comb),
//    cols j>=49 = -1e9 -> softmax zeros padding naturally
//  - in-register softmax via 16-lane shfl_xor reduce
//  - P hi/lo bf16 split via swizzled LDS image -> 2-term PV MFMA (precision)
//  - V transposed to LDS [32][64] swizzled -> conflict-free PV B-frags
// K1/K3 unchanged from round 5. Fallback: round-0 fp32 kernels.

#define DIMC   384
#define NTOK   49
#define NHEAD  12
#define HD     32
#define NWIN   64
#define BWIN   2048
#define SCALE  0.17677669529663687f  // 1/sqrt(32)

#define SLOT     4704                // ushorts per (b,h): 3*49*32
#define NBQ      9
#define NBP      3
#define FRAG_BLK 8192                // ushorts per (nb,kc): [2 hl][4 kq][128][8]

#define WS_SLOTS ((size_t)BWIN * NHEAD * SLOT)      // ushorts
#define WS_BFRAG ((size_t)NBQ * 12 * FRAG_BLK)
#define WS_PFRAG ((size_t)NBP * 12 * FRAG_BLK)
#define WS_COMB  ((size_t)NWIN * NHEAD * NTOK * 64) // floats
#define WS_NEED  ((WS_SLOTS + WS_BFRAG + WS_PFRAG) * 2 + WS_COMB * 4)  // bytes

typedef short bf16x8 __attribute__((ext_vector_type(8)));
typedef unsigned short u16x8 __attribute__((ext_vector_type(8)));
typedef float f32x4  __attribute__((ext_vector_type(4)));

__device__ __forceinline__ unsigned short f2bf(float f) {
    union { float f; unsigned u; } v; v.f = f;
    unsigned r = v.u + 0x7fffu + ((v.u >> 16) & 1u);   // RTN-even
    return (unsigned short)(r >> 16);
}
__device__ __forceinline__ float bf2f(unsigned short h) {
    union { unsigned u; float f; } v; v.u = ((unsigned)h) << 16;
    return v.f;
}
__device__ __forceinline__ void split2(float x, unsigned short& hi, unsigned short& lo) {
    hi = f2bf(x);
    lo = f2bf(x - bf2f(hi));
}
__device__ __forceinline__ float4 ld4(const float* p) {
    return *reinterpret_cast<const float4*>(p);
}
// async global->LDS, 16B/lane. LDS dest = wave-uniform base + lane*16.
__device__ __forceinline__ void gload16(const unsigned short* g, unsigned short* l) {
    __builtin_amdgcn_global_load_lds(
        (const __attribute__((address_space(1))) void*)g,
        (__attribute__((address_space(3))) void*)l, 16, 0, 0);
}

// ---------------------------------------------------------------------------
// K0a: pre-split a [384 x ncols] fp32 weight into hi/lo bf16 fragment blocks.
// ---------------------------------------------------------------------------
__global__ __launch_bounds__(256) void k_prep_w(
    const float* __restrict__ w, unsigned short* __restrict__ dst, int ncols)
{
    int f = blockIdx.x * 256 + threadIdx.x;
    if (f >= ncols * 48) return;
    int nb = f / 6144, rem = f - nb * 6144;     // 6144 = 12*4*128
    int kc = rem >> 9, rem2 = rem & 511;
    int kq = rem2 >> 7, rl = rem2 & 127;
    int n = nb * 128 + rl, k0 = kc * 32 + kq * 8;
    u16x8 h8, l8;
    #pragma unroll
    for (int e = 0; e < 8; ++e) {
        unsigned short hh, ll;
        split2(w[(size_t)(k0 + e) * ncols + n], hh, ll);
        h8[e] = hh; l8[e] = ll;
    }
    size_t base = ((size_t)(nb * 12 + kc) << 13) + (size_t)((kq << 7) + rl) * 8;
    *reinterpret_cast<u16x8*>(&dst[base])        = h8;
    *reinterpret_cast<u16x8*>(&dst[base + 4096]) = l8;
}

// ---------------------------------------------------------------------------
// K0b: comb[w*12+h][i(49)][j(64)] = mask[w][i][j] + bias_table[rel_idx[i][j]][h]
// for j<49, else -1e9 (padded cols vanish in softmax). 768 blocks.
// ---------------------------------------------------------------------------
__global__ __launch_bounds__(256) void k_prep_comb(
    const float* __restrict__ mask, const float* __restrict__ bias_table,
    const int* __restrict__ rel_idx, float* __restrict__ comb)
{
    int wh = blockIdx.x;            // w*12 + h
    int w = wh / NHEAD, h = wh - w * NHEAD;
    float* dst = comb + (size_t)wh * (NTOK * 64);
    for (int o = threadIdx.x; o < NTOK * 64; o += 256) {
        int i = o >> 6, j = o & 63;
        float v = -1e9f;
        if (j < NTOK) {
            int o2 = i * NTOK + j;
            v = mask[w * NTOK * NTOK + o2] + bias_table[rel_idx[o2] * NHEAD + h];
        }
        dst[o] = v;
    }
}

// ---------------------------------------------------------------------------
// K1: Y = X(100352x384) @ W(384x1152) + b, split-bf16 3-term MFMA,
// out bf16 to ws slots. Grid (784,9), block 256 (4 waves, 2x2).
// ---------------------------------------------------------------------------
__global__ __launch_bounds__(256) void k_gemm_qkv(
    const float* __restrict__ x, const unsigned short* __restrict__ Bfrag,
    const float* __restrict__ qb, unsigned short* __restrict__ ws)
{
    __shared__ __align__(16) unsigned short Als[FRAG_BLK];
    __shared__ __align__(16) unsigned short Bls[FRAG_BLK];

    const int t = threadIdx.x;
    const int wave = t >> 6, l = t & 63, lj = l & 15, quad = l >> 4;
    const int wm = wave & 1, wn = wave >> 1;
    const int gm0 = blockIdx.x * 128, gn0 = blockIdx.y * 128;

    const int fs0 = t, fs1 = t + 256;
    const float* xp0 = x + (size_t)(gm0 + (fs0 & 127)) * DIMC + (fs0 >> 7) * 8;
    const float* xp1 = x + (size_t)(gm0 + (fs1 & 127)) * DIMC + (fs1 >> 7) * 8;
    const unsigned short* Bg = Bfrag + (size_t)blockIdx.y * 12 * FRAG_BLK;

    f32x4 acc[4][4];
    #pragma unroll
    for (int i = 0; i < 4; ++i)
        #pragma unroll
        for (int j = 0; j < 4; ++j) acc[i][j] = (f32x4)0.0f;

    for (int kc = 0; kc < 12; ++kc) {
        #pragma unroll
        for (int c = 0; c < 4; ++c) {
            int ch = wave * 4 + c;
            gload16(Bg + (size_t)kc * FRAG_BLK + ch * 512 + l * 8, &Bls[ch * 512]);
        }
        {
            float4 x0 = ld4(xp0 + kc * 32), x1 = ld4(xp0 + kc * 32 + 4);
            u16x8 h8, l8; unsigned short hh, ll;
            split2(x0.x, hh, ll); h8[0] = hh; l8[0] = ll;
            split2(x0.y, hh, ll); h8[1] = hh; l8[1] = ll;
            split2(x0.z, hh, ll); h8[2] = hh; l8[2] = ll;
            split2(x0.w, hh, ll); h8[3] = hh; l8[3] = ll;
            split2(x1.x, hh, ll); h8[4] = hh; l8[4] = ll;
            split2(x1.y, hh, ll); h8[5] = hh; l8[5] = ll;
            split2(x1.z, hh, ll); h8[6] = hh; l8[6] = ll;
            split2(x1.w, hh, ll); h8[7] = hh; l8[7] = ll;
            *reinterpret_cast<u16x8*>(&Als[fs0 * 8])        = h8;
            *reinterpret_cast<u16x8*>(&Als[4096 + fs0 * 8]) = l8;
        }
        {
            float4 x0 = ld4(xp1 + kc * 32), x1 = ld4(xp1 + kc * 32 + 4);
            u16x8 h8, l8; unsigned short hh, ll;
            split2(x0.x, hh, ll); h8[0] = hh; l8[0] = ll;
            split2(x0.y, hh, ll); h8[1] = hh; l8[1] = ll;
            split2(x0.z, hh, ll); h8[2] = hh; l8[2] = ll;
            split2(x0.w, hh, ll); h8[3] = hh; l8[3] = ll;
            split2(x1.x, hh, ll); h8[4] = hh; l8[4] = ll;
            split2(x1.y, hh, ll); h8[5] = hh; l8[5] = ll;
            split2(x1.z, hh, ll); h8[6] = hh; l8[6] = ll;
            split2(x1.w, hh, ll); h8[7] = hh; l8[7] = ll;
            *reinterpret_cast<u16x8*>(&Als[fs1 * 8])        = h8;
            *reinterpret_cast<u16x8*>(&Als[4096 + fs1 * 8]) = l8;
        }
        __syncthreads();

        bf16x8 ah[4], al[4], bh[4], bl[4];
        #pragma unroll
        for (int i = 0; i < 4; ++i) {
            int ra = (quad * 128 + wm * 64 + i * 16 + lj) * 8;
            ah[i] = *reinterpret_cast<const bf16x8*>(&Als[ra]);
            al[i] = *reinterpret_cast<const bf16x8*>(&Als[4096 + ra]);
            int rb = (quad * 128 + wn * 64 + i * 16 + lj) * 8;
            bh[i] = *reinterpret_cast<const bf16x8*>(&Bls[rb]);
            bl[i] = *reinterpret_cast<const bf16x8*>(&Bls[4096 + rb]);
        }
        #pragma unroll
        for (int tm = 0; tm < 4; ++tm)
            #pragma unroll
            for (int tn = 0; tn < 4; ++tn) {
                acc[tm][tn] = __builtin_amdgcn_mfma_f32_16x16x32_bf16(ah[tm], bh[tn], acc[tm][tn], 0, 0, 0);
                acc[tm][tn] = __builtin_amdgcn_mfma_f32_16x16x32_bf16(ah[tm], bl[tn], acc[tm][tn], 0, 0, 0);
                acc[tm][tn] = __builtin_amdgcn_mfma_f32_16x16x32_bf16(al[tm], bh[tn], acc[tm][tn], 0, 0, 0);
            }
        __syncthreads();
    }

    #pragma unroll
    for (int tn = 0; tn < 4; ++tn) {
        int col = gn0 + wn * 64 + tn * 16 + lj;          // 0..1151
        float bias = qb[col];
        int part = col / 384, rem = col - part * 384;
        int h = rem >> 5, d = rem & 31;
        #pragma unroll
        for (int tm = 0; tm < 4; ++tm) {
            #pragma unroll
            for (int rr = 0; rr < 4; ++rr) {
                int row = gm0 + wm * 64 + tm * 16 + quad * 4 + rr;
                int b = row / 49, n = row - b * 49;
                size_t off = ((size_t)(b * NHEAD + h) * 3 + part) * 1568 + n * HD + d;
                ws[off] = f2bf(acc[tm][tn][rr] + bias);
            }
        }
    }
}

// ---------------------------------------------------------------------------
// K2: MFMA attention. Block = 128 (2 waves), each wave one (b,h).
// Pad 49->64: Q rows / K cols >=49 predicated to 0; comb cols >=49 = -1e9.
// Per wave: 16 MFMA QK -> scale+comb -> shfl softmax -> P hi/lo bf16 to
// swizzled LDS -> 32 MFMA PV with V^T staged swizzled -> bf16 out to q slot.
// LDS/block: 2*(16KB Pimg + 4KB Vt) = 40KB -> 4 blocks/CU.
// ---------------------------------------------------------------------------
__global__ __launch_bounds__(128) void k_attn_mfma(
    unsigned short* __restrict__ ws, const float* __restrict__ comb)
{
    __shared__ __align__(16) unsigned short Pimg[2][8192];  // hi plane | lo plane
    __shared__ __align__(16) unsigned short Vts[2][2048];   // V^T [32][64] swizzled

    const int t = threadIdx.x, wave = t >> 6, l = t & 63;
    const int lj = l & 15, quad = l >> 4;
    const int idx = blockIdx.x * 2 + wave;          // b*12 + h
    const int b = idx / NHEAD, h = idx - b * NHEAD;
    unsigned short* qp = ws + (size_t)idx * SLOT;
    const float* cb = comb + (size_t)((b & (NWIN - 1)) * NHEAD + h) * (NTOK * 64);
    unsigned short* pimg = Pimg[wave];
    unsigned short* vt   = Vts[wave];

    // zero Vt (padded cols j>=49 must be 0)
    #pragma unroll
    for (int it = 0; it < 4; ++it)
        *reinterpret_cast<u16x8*>(&vt[it * 512 + l * 8]) = (u16x8)0;

    // V chunk loads to regs: chunk c covers V[j = c>>2][d = (c&3)*8 .. +7]
    u16x8 vc[4];
    #pragma unroll
    for (int it = 0; it < 4; ++it) {
        int c = it * 64 + l;
        vc[it] = (c < 196)
            ? *reinterpret_cast<const u16x8*>(qp + 3136 + (c >> 2) * HD + (c & 3) * 8)
            : (u16x8)0;
    }

    // Q (A) and K (B) fragments straight from the slot (frag-order layout)
    bf16x8 aq[4], bk[4];
    #pragma unroll
    for (int mt = 0; mt < 4; ++mt) {
        int row = mt * 16 + lj;
        aq[mt] = (row < NTOK)
            ? *reinterpret_cast<const bf16x8*>(qp + row * HD + quad * 8) : (bf16x8)0;
        bk[mt] = (row < NTOK)
            ? *reinterpret_cast<const bf16x8*>(qp + 1568 + row * HD + quad * 8) : (bf16x8)0;
    }

    // QK^T: S[i][j], i = mt*16+quad*4+r, j = nt*16+lj
    f32x4 s[4][4];
    #pragma unroll
    for (int mt = 0; mt < 4; ++mt)
        #pragma unroll
        for (int nt = 0; nt < 4; ++nt)
            s[mt][nt] = __builtin_amdgcn_mfma_f32_16x16x32_bf16(aq[mt], bk[nt], (f32x4)0.0f, 0, 0, 0);

    // scale + bias/mask
    #pragma unroll
    for (int mt = 0; mt < 4; ++mt)
        #pragma unroll
        for (int r = 0; r < 4; ++r) {
            int i = mt * 16 + quad * 4 + r;
            #pragma unroll
            for (int nt = 0; nt < 4; ++nt) {
                float c = (i < NTOK) ? cb[i * 64 + nt * 16 + lj] : -1e9f;
                s[mt][nt][r] = fmaf(s[mt][nt][r], SCALE, c);
            }
        }

    __syncthreads();   // Vt zero visible block-wide

    // scatter V^T into LDS: vt[(d*64 + j) ^ ((d&7)<<3)]
    #pragma unroll
    for (int it = 0; it < 4; ++it) {
        int c = it * 64 + l;
        if (c < 196) {
            int j = c >> 2, dq = c & 3;
            #pragma unroll
            for (int e = 0; e < 8; ++e) {
                int d = dq * 8 + e;
                vt[(d * 64 + j) ^ ((d & 7) << 3)] = (unsigned short)vc[it][e];
            }
        }
    }

    // softmax per row (16 lanes share a row -> shfl_xor 1,2,4,8) + P hi/lo
    #pragma unroll
    for (int mt = 0; mt < 4; ++mt)
        #pragma unroll
        for (int r = 0; r < 4; ++r) {
            float m = fmaxf(fmaxf(s[mt][0][r], s[mt][1][r]),
                            fmaxf(s[mt][2][r], s[mt][3][r]));
            m = fmaxf(m, __shfl_xor(m, 1));
            m = fmaxf(m, __shfl_xor(m, 2));
            m = fmaxf(m, __shfl_xor(m, 4));
            m = fmaxf(m, __shfl_xor(m, 8));
            float e0 = __expf(s[mt][0][r] - m), e1 = __expf(s[mt][1][r] - m);
            float e2 = __expf(s[mt][2][r] - m), e3 = __expf(s[mt][3][r] - m);
            float sum = (e0 + e1) + (e2 + e3);
            sum += __shfl_xor(sum, 1);
            sum += __shfl_xor(sum, 2);
            sum += __shfl_xor(sum, 4);
            sum += __shfl_xor(sum, 8);
            float inv = 1.0f / sum;
            int i = mt * 16 + quad * 4 + r;
            int swz = (i & 7) << 3;
            float p0 = e0 * inv, p1 = e1 * inv, p2 = e2 * inv, p3 = e3 * inv;
            unsigned short hh, ll;
            split2(p0, hh, ll);
            pimg[(i * 64 +  0 + lj) ^ swz] = hh; pimg[4096 + ((i * 64 +  0 + lj) ^ swz)] = ll;
            split2(p1, hh, ll);
            pimg[(i * 64 + 16 + lj) ^ swz] = hh; pimg[4096 + ((i * 64 + 16 + lj) ^ swz)] = ll;
            split2(p2, hh, ll);
            pimg[(i * 64 + 32 + lj) ^ swz] = hh; pimg[4096 + ((i * 64 + 32 + lj) ^ swz)] = ll;
            split2(p3, hh, ll);
            pimg[(i * 64 + 48 + lj) ^ swz] = hh; pimg[4096 + ((i * 64 + 48 + lj) ^ swz)] = ll;
        }

    __syncthreads();   // P and V^T scatters complete

    // PV: O[i][d] = sum_j P[i][j] V[j][d]; A = P (hi+lo), B = V^T frags
    f32x4 o[4][2];
    #pragma unroll
    for (int mt = 0; mt < 4; ++mt) { o[mt][0] = (f32x4)0.0f; o[mt][1] = (f32x4)0.0f; }
    #pragma unroll
    for (int ks = 0; ks < 2; ++ks) {
        bf16x8 bv[2];
        #pragma unroll
        for (int nt = 0; nt < 2; ++nt) {
            int d = nt * 16 + lj;
            bv[nt] = *reinterpret_cast<const bf16x8*>(
                &vt[(d * 64 + ks * 32 + quad * 8) ^ ((d & 7) << 3)]);
        }
        #pragma unroll
        for (int mt = 0; mt < 4; ++mt) {
            int i = mt * 16 + lj;
            int fo = (i * 64 + ks * 32 + quad * 8) ^ ((i & 7) << 3);
            bf16x8 ph = *reinterpret_cast<const bf16x8*>(&pimg[fo]);
            bf16x8 pl = *reinterpret_cast<const bf16x8*>(&pimg[4096 + fo]);
            #pragma unroll
            for (int nt = 0; nt < 2; ++nt) {
                o[mt][nt] = __builtin_amdgcn_mfma_f32_16x16x32_bf16(ph, bv[nt], o[mt][nt], 0, 0, 0);
                o[mt][nt] = __builtin_amdgcn_mfma_f32_16x16x32_bf16(pl, bv[nt], o[mt][nt], 0, 0, 0);
            }
        }
    }

    // write O (bf16) over own q slot
    #pragma unroll
    for (int mt = 0; mt < 4; ++mt)
        #pragma unroll
        for (int r = 0; r < 4; ++r) {
            int i = mt * 16 + quad * 4 + r;
            if (i < NTOK) {
                qp[i * HD + lj]      = f2bf(o[mt][0][r]);
                qp[i * HD + 16 + lj] = f2bf(o[mt][1][r]);
            }
        }
}

// ---------------------------------------------------------------------------
// K3: out = Y2(100352x384 bf16 slots) @ proj_w + b, fp32 out. Grid (784,3).
// ---------------------------------------------------------------------------
__global__ __launch_bounds__(256) void k_gemm_proj(
    const unsigned short* __restrict__ ws, const unsigned short* __restrict__ Pfrag,
    const float* __restrict__ pbias, float* __restrict__ out)
{
    __shared__ __align__(16) unsigned short Als[4096];      // [4 kq][128][8], 8KB
    __shared__ __align__(16) unsigned short Bls[FRAG_BLK];  // hi/lo, 16KB

    const int t = threadIdx.x;
    const int wave = t >> 6, l = t & 63, lj = l & 15, quad = l >> 4;
    const int wm = wave & 1, wn = wave >> 1;
    const int gm0 = blockIdx.x * 128, gn0 = blockIdx.y * 128;

    const int ch0 = wave * 2, ch1 = wave * 2 + 1;
    size_t abase0, abase1;
    {
        int fs = ch0 * 64 + l;
        int kq = fs >> 7, rl = fs & 127, row = gm0 + rl;
        int b = row / 49, n = row - b * 49;
        abase0 = (size_t)(b * NHEAD) * SLOT + n * HD + kq * 8;
    }
    {
        int fs = ch1 * 64 + l;
        int kq = fs >> 7, rl = fs & 127, row = gm0 + rl;
        int b = row / 49, n = row - b * 49;
        abase1 = (size_t)(b * NHEAD) * SLOT + n * HD + kq * 8;
    }
    const unsigned short* Bg = Pfrag + (size_t)blockIdx.y * 12 * FRAG_BLK;

    f32x4 acc[4][4];
    #pragma unroll
    for (int i = 0; i < 4; ++i)
        #pragma unroll
        for (int j = 0; j < 4; ++j) acc[i][j] = (f32x4)0.0f;

    for (int kc = 0; kc < 12; ++kc) {       // kc == head index
        #pragma unroll
        for (int c = 0; c < 4; ++c) {
            int ch = wave * 4 + c;
            gload16(Bg + (size_t)kc * FRAG_BLK + ch * 512 + l * 8, &Bls[ch * 512]);
        }
        gload16(ws + abase0 + (size_t)kc * SLOT, &Als[ch0 * 512]);
        gload16(ws + abase1 + (size_t)kc * SLOT, &Als[ch1 * 512]);
        __syncthreads();

        bf16x8 a[4], bh[4], bl[4];
        #pragma unroll
        for (int i = 0; i < 4; ++i) {
            a[i] = *reinterpret_cast<const bf16x8*>(&Als[(quad * 128 + wm * 64 + i * 16 + lj) * 8]);
            int rb = (quad * 128 + wn * 64 + i * 16 + lj) * 8;
            bh[i] = *reinterpret_cast<const bf16x8*>(&Bls[rb]);
            bl[i] = *reinterpret_cast<const bf16x8*>(&Bls[4096 + rb]);
        }
        #pragma unroll
        for (int tm = 0; tm < 4; ++tm)
            #pragma unroll
            for (int tn = 0; tn < 4; ++tn) {
                acc[tm][tn] = __builtin_amdgcn_mfma_f32_16x16x32_bf16(a[tm], bh[tn], acc[tm][tn], 0, 0, 0);
                acc[tm][tn] = __builtin_amdgcn_mfma_f32_16x16x32_bf16(a[tm], bl[tn], acc[tm][tn], 0, 0, 0);
            }
        __syncthreads();
    }

    #pragma unroll
    for (int tn = 0; tn < 4; ++tn) {
        int col = gn0 + wn * 64 + tn * 16 + lj;
        float bias = pbias[col];
        #pragma unroll
        for (int tm = 0; tm < 4; ++tm)
            #pragma unroll
            for (int rr = 0; rr < 4; ++rr) {
                int row = gm0 + wm * 64 + tm * 16 + quad * 4 + rr;
                out[(size_t)row * DIMC + col] = acc[tm][tn][rr] + bias;
            }
    }
}

// ============================ fp32 fallback (round 0) =======================
__global__ __launch_bounds__(192) void k_qkv_attn(
    const float* __restrict__ x, const float* __restrict__ mask,
    const float* __restrict__ qkv_w, const float* __restrict__ qkv_b,
    const float* __restrict__ bias_table, const int* __restrict__ rel_idx,
    float* __restrict__ out)
{
    __shared__ __align__(16) float xs_t[64 * 68];
    __shared__ __align__(16) float qs[NTOK * HD];
    __shared__ __align__(16) float ks_[NTOK * HD];
    __shared__ __align__(16) float vs[NTOK * HD];
    __shared__ __align__(16) union { float w[64 * 96]; float s[NTOK * 56]; } u;

    const int t = threadIdx.x, b = blockIdx.x;
    const int tx = t % 12, ty = t / 12;
    const float* xb = x + (size_t)b * NTOK * DIMC;
    const int mbase = (b % NWIN) * NTOK * NTOK;

    for (int h = 0; h < NHEAD; ++h) {
        float acc[4][8];
        #pragma unroll
        for (int r = 0; r < 4; ++r)
            #pragma unroll
            for (int cc = 0; cc < 8; ++cc) acc[r][cc] = 0.0f;
        for (int c0 = 0; c0 < DIMC; c0 += 64) {
            for (int idx = t; idx < NTOK * 64; idx += 192) {
                int i = idx >> 6, kk2 = idx & 63;
                xs_t[kk2 * 68 + i] = xb[i * DIMC + c0 + kk2];
            }
            for (int idx = t; idx < 64 * 96; idx += 192) {
                int kk2 = idx / 96, c = idx % 96;
                int col = (c >> 5) * DIMC + h * HD + (c & 31);
                u.w[kk2 * 96 + c] = qkv_w[(size_t)(c0 + kk2) * (3 * DIMC) + col];
            }
            __syncthreads();
            #pragma unroll 8
            for (int kk2 = 0; kk2 < 64; ++kk2) {
                const float4 xv = ld4(&xs_t[kk2 * 68 + ty * 4]);
                const float4 w0 = ld4(&u.w[kk2 * 96 + tx * 8]);
                const float4 w1 = ld4(&u.w[kk2 * 96 + tx * 8 + 4]);
                const float xr[4] = {xv.x, xv.y, xv.z, xv.w};
                const float wc[8] = {w0.x, w0.y, w0.z, w0.w, w1.x, w1.y, w1.z, w1.w};
                #pragma unroll
                for (int r = 0; r < 4; ++r)
                    #pragma unroll
                    for (int cc = 0; cc < 8; ++cc)
                        acc[r][cc] = fmaf(xr[r], wc[cc], acc[r][cc]);
            }
            __syncthreads();
        }
        {
            const int part = tx >> 2, cbase = (tx & 3) * 8;
            float* dst = (part == 0) ? qs : (part == 1) ? ks_ : vs;
            #pragma unroll
            for (int r = 0; r < 4; ++r) {
                int i = ty * 4 + r;
                if (i < NTOK)
                    #pragma unroll
                    for (int cc = 0; cc < 8; ++cc) {
                        int c5 = cbase + cc;
                        dst[i * HD + c5] = acc[r][cc] + qkv_b[part * DIMC + h * HD + c5];
                    }
            }
        }
        __syncthreads();
        for (int o = t; o < NTOK * NTOK; o += 192) {
            int i = o / 49, j = o % 49;
            float4 a4 = {0.f, 0.f, 0.f, 0.f};
            #pragma unroll
            for (int seg = 0; seg < 8; ++seg) {
                float4 q4 = ld4(&qs[i * HD + seg * 4]);
                float4 k4 = ld4(&ks_[j * HD + seg * 4]);
                a4.x = fmaf(q4.x, k4.x, a4.x); a4.y = fmaf(q4.y, k4.y, a4.y);
                a4.z = fmaf(q4.z, k4.z, a4.z); a4.w = fmaf(q4.w, k4.w, a4.w);
            }
            u.s[i * 56 + j] = (a4.x + a4.y + a4.z + a4.w) * SCALE
                            + bias_table[rel_idx[o] * NHEAD + h] + mask[mbase + o];
        }
        __syncthreads();
        if (t < NTOK) {
            float* row = &u.s[t * 56];
            float m = row[0];
            for (int j = 1; j < NTOK; ++j) m = fmaxf(m, row[j]);
            float ssum = 0.f;
            for (int j = 0; j < NTOK; ++j) { float e = __expf(row[j] - m); row[j] = e; ssum += e; }
            float inv = 1.0f / ssum;
            for (int j = 0; j < NTOK; ++j) row[j] *= inv;
        }
        __syncthreads();
        for (int o = t; o < NTOK * 8; o += 192) {
            int i = o >> 3, dg = o & 7;
            float4 a = {0.f, 0.f, 0.f, 0.f};
            for (int j = 0; j < NTOK; ++j) {
                float sj = u.s[i * 56 + j];
                float4 v4 = ld4(&vs[j * HD + dg * 4]);
                a.x = fmaf(sj, v4.x, a.x); a.y = fmaf(sj, v4.y, a.y);
                a.z = fmaf(sj, v4.z, a.z); a.w = fmaf(sj, v4.w, a.w);
            }
            *reinterpret_cast<float4*>(&out[(size_t)(b * NTOK + i) * DIMC + h * HD + dg * 4]) = a;
        }
        __syncthreads();
    }
}

__global__ __launch_bounds__(192) void k_proj(
    float* __restrict__ io, const float* __restrict__ proj_w,
    const float* __restrict__ proj_b)
{
    __shared__ __align__(16) float ys_t[DIMC * 20];
    __shared__ __align__(16) float wch[16 * DIMC];
    const int t = threadIdx.x, row0 = blockIdx.x * 16;
    const int tx = t % 48, ty = t / 48;
    for (int idx = t; idx < 16 * DIMC; idx += 192) {
        int i = idx / DIMC, k = idx % DIMC;
        ys_t[k * 20 + i] = io[(size_t)(row0 + i) * DIMC + k];
    }
    float acc[4][8];
    #pragma unroll
    for (int r = 0; r < 4; ++r)
        #pragma unroll
        for (int cc = 0; cc < 8; ++cc) acc[r][cc] = 0.0f;
    for (int k0 = 0; k0 < DIMC; k0 += 16) {
        for (int idx = t; idx < 16 * DIMC; idx += 192) {
            int kk2 = idx / DIMC, c = idx % DIMC;
            wch[kk2 * DIMC + c] = proj_w[(size_t)(k0 + kk2) * DIMC + c];
        }
        __syncthreads();
        #pragma unroll
        for (int kk2 = 0; kk2 < 16; ++kk2) {
            const float4 xv = ld4(&ys_t[(k0 + kk2) * 20 + ty * 4]);
            const float4 w0 = ld4(&wch[kk2 * DIMC + tx * 8]);
            const float4 w1 = ld4(&wch[kk2 * DIMC + tx * 8 + 4]);
            const float xr[4] = {xv.x, xv.y, xv.z, xv.w};
            const float wc[8] = {w0.x, w0.y, w0.z, w0.w, w1.x, w1.y, w1.z, w1.w};
            #pragma unroll
            for (int r = 0; r < 4; ++r)
                #pragma unroll
                for (int cc = 0; cc < 8; ++cc)
                    acc[r][cc] = fmaf(xr[r], wc[cc], acc[r][cc]);
        }
        __syncthreads();
    }
    #pragma unroll
    for (int r = 0; r < 4; ++r) {
        int i = ty * 4 + r;
        float* dst = &io[(size_t)(row0 + i) * DIMC + tx * 8];
        #pragma unroll
        for (int cc = 0; cc < 8; ++cc) dst[cc] = acc[r][cc] + proj_b[tx * 8 + cc];
    }
}

extern "C" void kernel_launch(void* const* d_in, const int* in_sizes, int n_in,
                              void* d_out, int out_size, void* d_ws, size_t ws_size,
                              hipStream_t stream) {
    const float* x          = (const float*)d_in[0];
    const float* mask       = (const float*)d_in[1];
    const float* qkv_w      = (const float*)d_in[2];
    const float* qkv_b      = (const float*)d_in[3];
    const float* proj_w     = (const float*)d_in[4];
    const float* proj_b     = (const float*)d_in[5];
    const float* bias_table = (const float*)d_in[6];
    const int*   rel_idx    = (const int*)d_in[7];
    float* out = (float*)d_out;

    if (ws_size >= WS_NEED) {
        unsigned short* ws = (unsigned short*)d_ws;
        unsigned short* Bf = ws + WS_SLOTS;
        unsigned short* Pf = Bf + WS_BFRAG;
        float* combf = (float*)(Pf + WS_PFRAG);
        k_prep_w<<<216, 256, 0, stream>>>(qkv_w, Bf, 3 * DIMC);   // 55296 frags
        k_prep_w<<<72, 256, 0, stream>>>(proj_w, Pf, DIMC);       // 18432 frags
        k_prep_comb<<<NWIN * NHEAD, 256, 0, stream>>>(mask, bias_table, rel_idx, combf);
        dim3 g1(784, 9);
        k_gemm_qkv<<<g1, 256, 0, stream>>>(x, Bf, qkv_b, ws);
        k_attn_mfma<<<(BWIN * NHEAD) / 2, 128, 0, stream>>>(ws, combf);
        dim3 g3(784, 3);
        k_gemm_proj<<<g3, 256, 0, stream>>>(ws, Pf, proj_b, out);
    } else {
        k_qkv_attn<<<BWIN, 192, 0, stream>>>(x, mask, qkv_w, qkv_b,
                                             bias_table, rel_idx, out);
        k_proj<<<(BWIN * NTOK) / 16, 192, 0, stream>>>(out, proj_w, proj_b);
    }
}

// Round 11
// 815.529 us; speedup vs baseline: 2.2711x; 1.0115x over previous
//
#include <hip/hip_runtime.h>

// WindowAttention (Swin-style), MI355X. Round 8, eighth submission (r8-r15
// benches all hit infra failures — GPU broker at capacity; never measured).
// rocprof r7: k_gemm_qkv 438us (53%), MfmaUtil 26.5, VALUBusy 41.5, conflicts 0
// -> VALU-bound on manual fp32->hi/lo bf16 split (~160 VALU/thread/kc vs 230
// MFMA cycles); FETCH 694MB vs 154MB ideal (X re-streamed 9x, grid order).
// Fixes:
//  - split via v_cvt_pk_bf16_f32 (2 elems/op, RTE == old RTN-even): ~3x less VALU
//  - K1 grid (9,784), K3 grid (3,784): consecutive blocks share the A row-panel
//    -> X HBM-fetched ~once, L3/L2 serve re-reads
// K2 attention unchanged (MFMA tile, r6). Fallback: round-0 fp32 kernels.

#define DIMC   384
#define NTOK   49
#define NHEAD  12
#define HD     32
#define NWIN   64
#define BWIN   2048
#define SCALE  0.17677669529663687f  // 1/sqrt(32)

#define SLOT     4704                // ushorts per (b,h): 3*49*32
#define NBQ      9
#define NBP      3
#define FRAG_BLK 8192                // ushorts per (nb,kc): [2 hl][4 kq][128][8]

#define WS_SLOTS ((size_t)BWIN * NHEAD * SLOT)      // ushorts
#define WS_BFRAG ((size_t)NBQ * 12 * FRAG_BLK)
#define WS_PFRAG ((size_t)NBP * 12 * FRAG_BLK)
#define WS_COMB  ((size_t)NWIN * NHEAD * NTOK * 64) // floats
#define WS_NEED  ((WS_SLOTS + WS_BFRAG + WS_PFRAG) * 2 + WS_COMB * 4)  // bytes

typedef short bf16x8 __attribute__((ext_vector_type(8)));
typedef unsigned short u16x8 __attribute__((ext_vector_type(8)));
typedef unsigned u32x4 __attribute__((ext_vector_type(4)));
typedef float f32x4  __attribute__((ext_vector_type(4)));

__device__ __forceinline__ unsigned short f2bf(float f) {
    union { float f; unsigned u; } v; v.f = f;
    unsigned r = v.u + 0x7fffu + ((v.u >> 16) & 1u);   // RTN-even
    return (unsigned short)(r >> 16);
}
__device__ __forceinline__ float bf2f(unsigned short h) {
    union { unsigned u; float f; } v; v.u = ((unsigned)h) << 16;
    return v.f;
}
__device__ __forceinline__ void split2(float x, unsigned short& hi, unsigned short& lo) {
    hi = f2bf(x);
    lo = f2bf(x - bf2f(hi));
}
// packed bf16 convert (RTE, == RTN-even for normals): lo16=bf16(a), hi16=bf16(b)
__device__ __forceinline__ unsigned cvtpk(float a, float b) {
    unsigned r;
    asm("v_cvt_pk_bf16_f32 %0, %1, %2" : "=v"(r) : "v"(a), "v"(b));
    return r;
}
__device__ __forceinline__ unsigned lopk(float a, float b, unsigned h) {
    union { unsigned u; float f; } h0, h1;
    h0.u = h << 16; h1.u = h & 0xffff0000u;
    return cvtpk(a - h0.f, b - h1.f);
}
// 8 fp32 -> packed hi plane (4 u32) + lo plane (4 u32)
__device__ __forceinline__ void splitpk8(float4 a, float4 b, u32x4& h, u32x4& l) {
    h[0] = cvtpk(a.x, a.y); h[1] = cvtpk(a.z, a.w);
    h[2] = cvtpk(b.x, b.y); h[3] = cvtpk(b.z, b.w);
    l[0] = lopk(a.x, a.y, h[0]); l[1] = lopk(a.z, a.w, h[1]);
    l[2] = lopk(b.x, b.y, h[2]); l[3] = lopk(b.z, b.w, h[3]);
}
__device__ __forceinline__ float4 ld4(const float* p) {
    return *reinterpret_cast<const float4*>(p);
}
// async global->LDS, 16B/lane. LDS dest = wave-uniform base + lane*16.
__device__ __forceinline__ void gload16(const unsigned short* g, unsigned short* l) {
    __builtin_amdgcn_global_load_lds(
        (const __attribute__((address_space(1))) void*)g,
        (__attribute__((address_space(3))) void*)l, 16, 0, 0);
}

// ---------------------------------------------------------------------------
// K0a: pre-split a [384 x ncols] fp32 weight into hi/lo bf16 fragment blocks.
// ---------------------------------------------------------------------------
__global__ __launch_bounds__(256) void k_prep_w(
    const float* __restrict__ w, unsigned short* __restrict__ dst, int ncols)
{
    int f = blockIdx.x * 256 + threadIdx.x;
    if (f >= ncols * 48) return;
    int nb = f / 6144, rem = f - nb * 6144;     // 6144 = 12*4*128
    int kc = rem >> 9, rem2 = rem & 511;
    int kq = rem2 >> 7, rl = rem2 & 127;
    int n = nb * 128 + rl, k0 = kc * 32 + kq * 8;
    u16x8 h8, l8;
    #pragma unroll
    for (int e = 0; e < 8; ++e) {
        unsigned short hh, ll;
        split2(w[(size_t)(k0 + e) * ncols + n], hh, ll);
        h8[e] = hh; l8[e] = ll;
    }
    size_t base = ((size_t)(nb * 12 + kc) << 13) + (size_t)((kq << 7) + rl) * 8;
    *reinterpret_cast<u16x8*>(&dst[base])        = h8;
    *reinterpret_cast<u16x8*>(&dst[base + 4096]) = l8;
}

// ---------------------------------------------------------------------------
// K0b: comb[w*12+h][i(49)][j(64)] = mask[w][i][j] + bias_table[rel_idx[i][j]][h]
// for j<49, else -1e9 (padded cols vanish in softmax). 768 blocks.
// ---------------------------------------------------------------------------
__global__ __launch_bounds__(256) void k_prep_comb(
    const float* __restrict__ mask, const float* __restrict__ bias_table,
    const int* __restrict__ rel_idx, float* __restrict__ comb)
{
    int wh = blockIdx.x;            // w*12 + h
    int w = wh / NHEAD, h = wh - w * NHEAD;
    float* dst = comb + (size_t)wh * (NTOK * 64);
    for (int o = threadIdx.x; o < NTOK * 64; o += 256) {
        int i = o >> 6, j = o & 63;
        float v = -1e9f;
        if (j < NTOK) {
            int o2 = i * NTOK + j;
            v = mask[w * NTOK * NTOK + o2] + bias_table[rel_idx[o2] * NHEAD + h];
        }
        dst[o] = v;
    }
}

// ---------------------------------------------------------------------------
// K1: Y = X(100352x384) @ W(384x1152) + b, split-bf16 3-term MFMA,
// out bf16 to ws slots. Grid (9,784): x = column-panel (fast) -> 9
// consecutive blocks share one A row-panel (L2/L3 locality). Block 256.
// ---------------------------------------------------------------------------
__global__ __launch_bounds__(256) void k_gemm_qkv(
    const float* __restrict__ x, const unsigned short* __restrict__ Bfrag,
    const float* __restrict__ qb, unsigned short* __restrict__ ws)
{
    __shared__ __align__(16) unsigned short Als[FRAG_BLK];
    __shared__ __align__(16) unsigned short Bls[FRAG_BLK];

    const int t = threadIdx.x;
    const int wave = t >> 6, l = t & 63, lj = l & 15, quad = l >> 4;
    const int wm = wave & 1, wn = wave >> 1;
    const int gm0 = blockIdx.y * 128, gn0 = blockIdx.x * 128;

    const int fs0 = t, fs1 = t + 256;
    const float* xp0 = x + (size_t)(gm0 + (fs0 & 127)) * DIMC + (fs0 >> 7) * 8;
    const float* xp1 = x + (size_t)(gm0 + (fs1 & 127)) * DIMC + (fs1 >> 7) * 8;
    const unsigned short* Bg = Bfrag + (size_t)blockIdx.x * 12 * FRAG_BLK;

    f32x4 acc[4][4];
    #pragma unroll
    for (int i = 0; i < 4; ++i)
        #pragma unroll
        for (int j = 0; j < 4; ++j) acc[i][j] = (f32x4)0.0f;

    for (int kc = 0; kc < 12; ++kc) {
        #pragma unroll
        for (int c = 0; c < 4; ++c) {
            int ch = wave * 4 + c;
            gload16(Bg + (size_t)kc * FRAG_BLK + ch * 512 + l * 8, &Bls[ch * 512]);
        }
        {
            float4 x0 = ld4(xp0 + kc * 32), x1 = ld4(xp0 + kc * 32 + 4);
            u32x4 h, lo;
            splitpk8(x0, x1, h, lo);
            *reinterpret_cast<u32x4*>(&Als[fs0 * 8])        = h;
            *reinterpret_cast<u32x4*>(&Als[4096 + fs0 * 8]) = lo;
        }
        {
            float4 x0 = ld4(xp1 + kc * 32), x1 = ld4(xp1 + kc * 32 + 4);
            u32x4 h, lo;
            splitpk8(x0, x1, h, lo);
            *reinterpret_cast<u32x4*>(&Als[fs1 * 8])        = h;
            *reinterpret_cast<u32x4*>(&Als[4096 + fs1 * 8]) = lo;
        }
        __syncthreads();

        bf16x8 ah[4], al[4], bh[4], bl[4];
        #pragma unroll
        for (int i = 0; i < 4; ++i) {
            int ra = (quad * 128 + wm * 64 + i * 16 + lj) * 8;
            ah[i] = *reinterpret_cast<const bf16x8*>(&Als[ra]);
            al[i] = *reinterpret_cast<const bf16x8*>(&Als[4096 + ra]);
            int rb = (quad * 128 + wn * 64 + i * 16 + lj) * 8;
            bh[i] = *reinterpret_cast<const bf16x8*>(&Bls[rb]);
            bl[i] = *reinterpret_cast<const bf16x8*>(&Bls[4096 + rb]);
        }
        #pragma unroll
        for (int tm = 0; tm < 4; ++tm)
            #pragma unroll
            for (int tn = 0; tn < 4; ++tn) {
                acc[tm][tn] = __builtin_amdgcn_mfma_f32_16x16x32_bf16(ah[tm], bh[tn], acc[tm][tn], 0, 0, 0);
                acc[tm][tn] = __builtin_amdgcn_mfma_f32_16x16x32_bf16(ah[tm], bl[tn], acc[tm][tn], 0, 0, 0);
                acc[tm][tn] = __builtin_amdgcn_mfma_f32_16x16x32_bf16(al[tm], bh[tn], acc[tm][tn], 0, 0, 0);
            }
        __syncthreads();
    }

    #pragma unroll
    for (int tn = 0; tn < 4; ++tn) {
        int col = gn0 + wn * 64 + tn * 16 + lj;          // 0..1151
        float bias = qb[col];
        int part = col / 384, rem = col - part * 384;
        int h = rem >> 5, d = rem & 31;
        #pragma unroll
        for (int tm = 0; tm < 4; ++tm) {
            #pragma unroll
            for (int rr = 0; rr < 4; ++rr) {
                int row = gm0 + wm * 64 + tm * 16 + quad * 4 + rr;
                int b = row / 49, n = row - b * 49;
                size_t off = ((size_t)(b * NHEAD + h) * 3 + part) * 1568 + n * HD + d;
                ws[off] = f2bf(acc[tm][tn][rr] + bias);
            }
        }
    }
}

// ---------------------------------------------------------------------------
// K2: MFMA attention. Block = 128 (2 waves), each wave one (b,h).
// Pad 49->64: Q rows / K cols >=49 predicated to 0; comb cols >=49 = -1e9.
// Per wave: 16 MFMA QK -> scale+comb -> shfl softmax -> P hi/lo bf16 to
// swizzled LDS -> 32 MFMA PV with V^T staged swizzled -> bf16 out to q slot.
// LDS/block: 2*(16KB Pimg + 4KB Vt) = 40KB -> 4 blocks/CU.
// ---------------------------------------------------------------------------
__global__ __launch_bounds__(128) void k_attn_mfma(
    unsigned short* __restrict__ ws, const float* __restrict__ comb)
{
    __shared__ __align__(16) unsigned short Pimg[2][8192];  // hi plane | lo plane
    __shared__ __align__(16) unsigned short Vts[2][2048];   // V^T [32][64] swizzled

    const int t = threadIdx.x, wave = t >> 6, l = t & 63;
    const int lj = l & 15, quad = l >> 4;
    const int idx = blockIdx.x * 2 + wave;          // b*12 + h
    const int b = idx / NHEAD, h = idx - b * NHEAD;
    unsigned short* qp = ws + (size_t)idx * SLOT;
    const float* cb = comb + (size_t)((b & (NWIN - 1)) * NHEAD + h) * (NTOK * 64);
    unsigned short* pimg = Pimg[wave];
    unsigned short* vt   = Vts[wave];

    // zero Vt (padded cols j>=49 must be 0)
    #pragma unroll
    for (int it = 0; it < 4; ++it)
        *reinterpret_cast<u16x8*>(&vt[it * 512 + l * 8]) = (u16x8)0;

    // V chunk loads to regs: chunk c covers V[j = c>>2][d = (c&3)*8 .. +7]
    u16x8 vc[4];
    #pragma unroll
    for (int it = 0; it < 4; ++it) {
        int c = it * 64 + l;
        vc[it] = (c < 196)
            ? *reinterpret_cast<const u16x8*>(qp + 3136 + (c >> 2) * HD + (c & 3) * 8)
            : (u16x8)0;
    }

    // Q (A) and K (B) fragments straight from the slot (frag-order layout)
    bf16x8 aq[4], bk[4];
    #pragma unroll
    for (int mt = 0; mt < 4; ++mt) {
        int row = mt * 16 + lj;
        aq[mt] = (row < NTOK)
            ? *reinterpret_cast<const bf16x8*>(qp + row * HD + quad * 8) : (bf16x8)0;
        bk[mt] = (row < NTOK)
            ? *reinterpret_cast<const bf16x8*>(qp + 1568 + row * HD + quad * 8) : (bf16x8)0;
    }

    // QK^T: S[i][j], i = mt*16+quad*4+r, j = nt*16+lj
    f32x4 s[4][4];
    #pragma unroll
    for (int mt = 0; mt < 4; ++mt)
        #pragma unroll
        for (int nt = 0; nt < 4; ++nt)
            s[mt][nt] = __builtin_amdgcn_mfma_f32_16x16x32_bf16(aq[mt], bk[nt], (f32x4)0.0f, 0, 0, 0);

    // scale + bias/mask
    #pragma unroll
    for (int mt = 0; mt < 4; ++mt)
        #pragma unroll
        for (int r = 0; r < 4; ++r) {
            int i = mt * 16 + quad * 4 + r;
            #pragma unroll
            for (int nt = 0; nt < 4; ++nt) {
                float c = (i < NTOK) ? cb[i * 64 + nt * 16 + lj] : -1e9f;
                s[mt][nt][r] = fmaf(s[mt][nt][r], SCALE, c);
            }
        }

    __syncthreads();   // Vt zero visible block-wide

    // scatter V^T into LDS: vt[(d*64 + j) ^ ((d&7)<<3)]
    #pragma unroll
    for (int it = 0; it < 4; ++it) {
        int c = it * 64 + l;
        if (c < 196) {
            int j = c >> 2, dq = c & 3;
            #pragma unroll
            for (int e = 0; e < 8; ++e) {
                int d = dq * 8 + e;
                vt[(d * 64 + j) ^ ((d & 7) << 3)] = (unsigned short)vc[it][e];
            }
        }
    }

    // softmax per row (16 lanes share a row -> shfl_xor 1,2,4,8) + P hi/lo
    #pragma unroll
    for (int mt = 0; mt < 4; ++mt)
        #pragma unroll
        for (int r = 0; r < 4; ++r) {
            float m = fmaxf(fmaxf(s[mt][0][r], s[mt][1][r]),
                            fmaxf(s[mt][2][r], s[mt][3][r]));
            m = fmaxf(m, __shfl_xor(m, 1));
            m = fmaxf(m, __shfl_xor(m, 2));
            m = fmaxf(m, __shfl_xor(m, 4));
            m = fmaxf(m, __shfl_xor(m, 8));
            float e0 = __expf(s[mt][0][r] - m), e1 = __expf(s[mt][1][r] - m);
            float e2 = __expf(s[mt][2][r] - m), e3 = __expf(s[mt][3][r] - m);
            float sum = (e0 + e1) + (e2 + e3);
            sum += __shfl_xor(sum, 1);
            sum += __shfl_xor(sum, 2);
            sum += __shfl_xor(sum, 4);
            sum += __shfl_xor(sum, 8);
            float inv = 1.0f / sum;
            int i = mt * 16 + quad * 4 + r;
            int swz = (i & 7) << 3;
            float p0 = e0 * inv, p1 = e1 * inv, p2 = e2 * inv, p3 = e3 * inv;
            unsigned short hh, ll;
            split2(p0, hh, ll);
            pimg[(i * 64 +  0 + lj) ^ swz] = hh; pimg[4096 + ((i * 64 +  0 + lj) ^ swz)] = ll;
            split2(p1, hh, ll);
            pimg[(i * 64 + 16 + lj) ^ swz] = hh; pimg[4096 + ((i * 64 + 16 + lj) ^ swz)] = ll;
            split2(p2, hh, ll);
            pimg[(i * 64 + 32 + lj) ^ swz] = hh; pimg[4096 + ((i * 64 + 32 + lj) ^ swz)] = ll;
            split2(p3, hh, ll);
            pimg[(i * 64 + 48 + lj) ^ swz] = hh; pimg[4096 + ((i * 64 + 48 + lj) ^ swz)] = ll;
        }

    __syncthreads();   // P and V^T scatters complete

    // PV: O[i][d] = sum_j P[i][j] V[j][d]; A = P (hi+lo), B = V^T frags
    f32x4 o[4][2];
    #pragma unroll
    for (int mt = 0; mt < 4; ++mt) { o[mt][0] = (f32x4)0.0f; o[mt][1] = (f32x4)0.0f; }
    #pragma unroll
    for (int ks = 0; ks < 2; ++ks) {
        bf16x8 bv[2];
        #pragma unroll
        for (int nt = 0; nt < 2; ++nt) {
            int d = nt * 16 + lj;
            bv[nt] = *reinterpret_cast<const bf16x8*>(
                &vt[(d * 64 + ks * 32 + quad * 8) ^ ((d & 7) << 3)]);
        }
        #pragma unroll
        for (int mt = 0; mt < 4; ++mt) {
            int i = mt * 16 + lj;
            int fo = (i * 64 + ks * 32 + quad * 8) ^ ((i & 7) << 3);
            bf16x8 ph = *reinterpret_cast<const bf16x8*>(&pimg[fo]);
            bf16x8 pl = *reinterpret_cast<const bf16x8*>(&pimg[4096 + fo]);
            #pragma unroll
            for (int nt = 0; nt < 2; ++nt) {
                o[mt][nt] = __builtin_amdgcn_mfma_f32_16x16x32_bf16(ph, bv[nt], o[mt][nt], 0, 0, 0);
                o[mt][nt] = __builtin_amdgcn_mfma_f32_16x16x32_bf16(pl, bv[nt], o[mt][nt], 0, 0, 0);
            }
        }
    }

    // write O (bf16) over own q slot
    #pragma unroll
    for (int mt = 0; mt < 4; ++mt)
        #pragma unroll
        for (int r = 0; r < 4; ++r) {
            int i = mt * 16 + quad * 4 + r;
            if (i < NTOK) {
                qp[i * HD + lj]      = f2bf(o[mt][0][r]);
                qp[i * HD + 16 + lj] = f2bf(o[mt][1][r]);
            }
        }
}

// ---------------------------------------------------------------------------
// K3: out = Y2(100352x384 bf16 slots) @ proj_w + b, fp32 out. Grid (3,784):
// x = column-panel (fast) -> 3 consecutive blocks share one A row-panel.
// ---------------------------------------------------------------------------
__global__ __launch_bounds__(256) void k_gemm_proj(
    const unsigned short* __restrict__ ws, const unsigned short* __restrict__ Pfrag,
    const float* __restrict__ pbias, float* __restrict__ out)
{
    __shared__ __align__(16) unsigned short Als[4096];      // [4 kq][128][8], 8KB
    __shared__ __align__(16) unsigned short Bls[FRAG_BLK];  // hi/lo, 16KB

    const int t = threadIdx.x;
    const int wave = t >> 6, l = t & 63, lj = l & 15, quad = l >> 4;
    const int wm = wave & 1, wn = wave >> 1;
    const int gm0 = blockIdx.y * 128, gn0 = blockIdx.x * 128;

    const int ch0 = wave * 2, ch1 = wave * 2 + 1;
    size_t abase0, abase1;
    {
        int fs = ch0 * 64 + l;
        int kq = fs >> 7, rl = fs & 127, row = gm0 + rl;
        int b = row / 49, n = row - b * 49;
        abase0 = (size_t)(b * NHEAD) * SLOT + n * HD + kq * 8;
    }
    {
        int fs = ch1 * 64 + l;
        int kq = fs >> 7, rl = fs & 127, row = gm0 + rl;
        int b = row / 49, n = row - b * 49;
        abase1 = (size_t)(b * NHEAD) * SLOT + n * HD + kq * 8;
    }
    const unsigned short* Bg = Pfrag + (size_t)blockIdx.x * 12 * FRAG_BLK;

    f32x4 acc[4][4];
    #pragma unroll
    for (int i = 0; i < 4; ++i)
        #pragma unroll
        for (int j = 0; j < 4; ++j) acc[i][j] = (f32x4)0.0f;

    for (int kc = 0; kc < 12; ++kc) {       // kc == head index
        #pragma unroll
        for (int c = 0; c < 4; ++c) {
            int ch = wave * 4 + c;
            gload16(Bg + (size_t)kc * FRAG_BLK + ch * 512 + l * 8, &Bls[ch * 512]);
        }
        gload16(ws + abase0 + (size_t)kc * SLOT, &Als[ch0 * 512]);
        gload16(ws + abase1 + (size_t)kc * SLOT, &Als[ch1 * 512]);
        __syncthreads();

        bf16x8 a[4], bh[4], bl[4];
        #pragma unroll
        for (int i = 0; i < 4; ++i) {
            a[i] = *reinterpret_cast<const bf16x8*>(&Als[(quad * 128 + wm * 64 + i * 16 + lj) * 8]);
            int rb = (quad * 128 + wn * 64 + i * 16 + lj) * 8;
            bh[i] = *reinterpret_cast<const bf16x8*>(&Bls[rb]);
            bl[i] = *reinterpret_cast<const bf16x8*>(&Bls[4096 + rb]);
        }
        #pragma unroll
        for (int tm = 0; tm < 4; ++tm)
            #pragma unroll
            for (int tn = 0; tn < 4; ++tn) {
                acc[tm][tn] = __builtin_amdgcn_mfma_f32_16x16x32_bf16(a[tm], bh[tn], acc[tm][tn], 0, 0, 0);
                acc[tm][tn] = __builtin_amdgcn_mfma_f32_16x16x32_bf16(a[tm], bl[tn], acc[tm][tn], 0, 0, 0);
            }
        __syncthreads();
    }

    #pragma unroll
    for (int tn = 0; tn < 4; ++tn) {
        int col = gn0 + wn * 64 + tn * 16 + lj;
        float bias = pbias[col];
        #pragma unroll
        for (int tm = 0; tm < 4; ++tm)
            #pragma unroll
            for (int rr = 0; rr < 4; ++rr) {
                int row = gm0 + wm * 64 + tm * 16 + quad * 4 + rr;
                out[(size_t)row * DIMC + col] = acc[tm][tn][rr] + bias;
            }
    }
}

// ============================ fp32 fallback (round 0) =======================
__global__ __launch_bounds__(192) void k_qkv_attn(
    const float* __restrict__ x, const float* __restrict__ mask,
    const float* __restrict__ qkv_w, const float* __restrict__ qkv_b,
    const float* __restrict__ bias_table, const int* __restrict__ rel_idx,
    float* __restrict__ out)
{
    __shared__ __align__(16) float xs_t[64 * 68];
    __shared__ __align__(16) float qs[NTOK * HD];
    __shared__ __align__(16) float ks_[NTOK * HD];
    __shared__ __align__(16) float vs[NTOK * HD];
    __shared__ __align__(16) union { float w[64 * 96]; float s[NTOK * 56]; } u;

    const int t = threadIdx.x, b = blockIdx.x;
    const int tx = t % 12, ty = t / 12;
    const float* xb = x + (size_t)b * NTOK * DIMC;
    const int mbase = (b % NWIN) * NTOK * NTOK;

    for (int h = 0; h < NHEAD; ++h) {
        float acc[4][8];
        #pragma unroll
        for (int r = 0; r < 4; ++r)
            #pragma unroll
            for (int cc = 0; cc < 8; ++cc) acc[r][cc] = 0.0f;
        for (int c0 = 0; c0 < DIMC; c0 += 64) {
            for (int idx = t; idx < NTOK * 64; idx += 192) {
                int i = idx >> 6, kk2 = idx & 63;
                xs_t[kk2 * 68 + i] = xb[i * DIMC + c0 + kk2];
            }
            for (int idx = t; idx < 64 * 96; idx += 192) {
                int kk2 = idx / 96, c = idx % 96;
                int col = (c >> 5) * DIMC + h * HD + (c & 31);
                u.w[kk2 * 96 + c] = qkv_w[(size_t)(c0 + kk2) * (3 * DIMC) + col];
            }
            __syncthreads();
            #pragma unroll 8
            for (int kk2 = 0; kk2 < 64; ++kk2) {
                const float4 xv = ld4(&xs_t[kk2 * 68 + ty * 4]);
                const float4 w0 = ld4(&u.w[kk2 * 96 + tx * 8]);
                const float4 w1 = ld4(&u.w[kk2 * 96 + tx * 8 + 4]);
                const float xr[4] = {xv.x, xv.y, xv.z, xv.w};
                const float wc[8] = {w0.x, w0.y, w0.z, w0.w, w1.x, w1.y, w1.z, w1.w};
                #pragma unroll
                for (int r = 0; r < 4; ++r)
                    #pragma unroll
                    for (int cc = 0; cc < 8; ++cc)
                        acc[r][cc] = fmaf(xr[r], wc[cc], acc[r][cc]);
            }
            __syncthreads();
        }
        {
            const int part = tx >> 2, cbase = (tx & 3) * 8;
            float* dst = (part == 0) ? qs : (part == 1) ? ks_ : vs;
            #pragma unroll
            for (int r = 0; r < 4; ++r) {
                int i = ty * 4 + r;
                if (i < NTOK)
                    #pragma unroll
                    for (int cc = 0; cc < 8; ++cc) {
                        int c5 = cbase + cc;
                        dst[i * HD + c5] = acc[r][cc] + qkv_b[part * DIMC + h * HD + c5];
                    }
            }
        }
        __syncthreads();
        for (int o = t; o < NTOK * NTOK; o += 192) {
            int i = o / 49, j = o % 49;
            float4 a4 = {0.f, 0.f, 0.f, 0.f};
            #pragma unroll
            for (int seg = 0; seg < 8; ++seg) {
                float4 q4 = ld4(&qs[i * HD + seg * 4]);
                float4 k4 = ld4(&ks_[j * HD + seg * 4]);
                a4.x = fmaf(q4.x, k4.x, a4.x); a4.y = fmaf(q4.y, k4.y, a4.y);
                a4.z = fmaf(q4.z, k4.z, a4.z); a4.w = fmaf(q4.w, k4.w, a4.w);
            }
            u.s[i * 56 + j] = (a4.x + a4.y + a4.z + a4.w) * SCALE
                            + bias_table[rel_idx[o] * NHEAD + h] + mask[mbase + o];
        }
        __syncthreads();
        if (t < NTOK) {
            float* row = &u.s[t * 56];
            float m = row[0];
            for (int j = 1; j < NTOK; ++j) m = fmaxf(m, row[j]);
            float ssum = 0.f;
            for (int j = 0; j < NTOK; ++j) { float e = __expf(row[j] - m); row[j] = e; ssum += e; }
            float inv = 1.0f / ssum;
            for (int j = 0; j < NTOK; ++j) row[j] *= inv;
        }
        __syncthreads();
        for (int o = t; o < NTOK * 8; o += 192) {
            int i = o >> 3, dg = o & 7;
            float4 a = {0.f, 0.f, 0.f, 0.f};
            for (int j = 0; j < NTOK; ++j) {
                float sj = u.s[i * 56 + j];
                float4 v4 = ld4(&vs[j * HD + dg * 4]);
                a.x = fmaf(sj, v4.x, a.x); a.y = fmaf(sj, v4.y, a.y);
                a.z = fmaf(sj, v4.z, a.z); a.w = fmaf(sj, v4.w, a.w);
            }
            *reinterpret_cast<float4*>(&out[(size_t)(b * NTOK + i) * DIMC + h * HD + dg * 4]) = a;
        }
        __syncthreads();
    }
}

__global__ __launch_bounds__(192) void k_proj(
    float* __restrict__ io, const float* __restrict__ proj_w,
    const float* __restrict__ proj_b)
{
    __shared__ __align__(16) float ys_t[DIMC * 20];
    __shared__ __align__(16) float wch[16 * DIMC];
    const int t = threadIdx.x, row0 = blockIdx.x * 16;
    const int tx = t % 48, ty = t / 48;
    for (int idx = t; idx < 16 * DIMC; idx += 192) {
        int i = idx / DIMC, k = idx % DIMC;
        ys_t[k * 20 + i] = io[(size_t)(row0 + i) * DIMC + k];
    }
    float acc[4][8];
    #pragma unroll
    for (int r = 0; r < 4; ++r)
        #pragma unroll
        for (int cc = 0; cc < 8; ++cc) acc[r][cc] = 0.0f;
    for (int k0 = 0; k0 < DIMC; k0 += 16) {
        for (int idx = t; idx < 16 * DIMC; idx += 192) {
            int kk2 = idx / DIMC, c = idx % DIMC;
            wch[kk2 * DIMC + c] = proj_w[(size_t)(k0 + kk2) * DIMC + c];
        }
        __syncthreads();
        #pragma unroll
        for (int kk2 = 0; kk2 < 16; ++kk2) {
            const float4 xv = ld4(&ys_t[(k0 + kk2) * 20 + ty * 4]);
            const float4 w0 = ld4(&wch[kk2 * DIMC + tx * 8]);
            const float4 w1 = ld4(&wch[kk2 * DIMC + tx * 8 + 4]);
            const float xr[4] = {xv.x, xv.y, xv.z, xv.w};
            const float wc[8] = {w0.x, w0.y, w0.z, w0.w, w1.x, w1.y, w1.z, w1.w};
            #pragma unroll
            for (int r = 0; r < 4; ++r)
                #pragma unroll
                for (int cc = 0; cc < 8; ++cc)
                    acc[r][cc] = fmaf(xr[r], wc[cc], acc[r][cc]);
        }
        __syncthreads();
    }
    #pragma unroll
    for (int r = 0; r < 4; ++r) {
        int i = ty * 4 + r;
        float* dst = &io[(size_t)(row0 + i) * DIMC + tx * 8];
        #pragma unroll
        for (int cc = 0; cc < 8; ++cc) dst[cc] = acc[r][cc] + proj_b[tx * 8 + cc];
    }
}

extern "C" void kernel_launch(void* const* d_in, const int* in_sizes, int n_in,
                              void* d_out, int out_size, void* d_ws, size_t ws_size,
                              hipStream_t stream) {
    const float* x          = (const float*)d_in[0];
    const float* mask       = (const float*)d_in[1];
    const float* qkv_w      = (const float*)d_in[2];
    const float* qkv_b      = (const float*)d_in[3];
    const float* proj_w     = (const float*)d_in[4];
    const float* proj_b     = (const float*)d_in[5];
    const float* bias_table = (const float*)d_in[6];
    const int*   rel_idx    = (const int*)d_in[7];
    float* out = (float*)d_out;

    if (ws_size >= WS_NEED) {
        unsigned short* ws = (unsigned short*)d_ws;
        unsigned short* Bf = ws + WS_SLOTS;
        unsigned short* Pf = Bf + WS_BFRAG;
        float* combf = (float*)(Pf + WS_PFRAG);
        k_prep_w<<<216, 256, 0, stream>>>(qkv_w, Bf, 3 * DIMC);   // 55296 frags
        k_prep_w<<<72, 256, 0, stream>>>(proj_w, Pf, DIMC);       // 18432 frags
        k_prep_comb<<<NWIN * NHEAD, 256, 0, stream>>>(mask, bias_table, rel_idx, combf);
        dim3 g1(9, 784);
        k_gemm_qkv<<<g1, 256, 0, stream>>>(x, Bf, qkv_b, ws);
        k_attn_mfma<<<(BWIN * NHEAD) / 2, 128, 0, stream>>>(ws, combf);
        dim3 g3(3, 784);
        k_gemm_proj<<<g3, 256, 0, stream>>>(ws, Pf, proj_b, out);
    } else {
        k_qkv_attn<<<BWIN, 192, 0, stream>>>(x, mask, qkv_w, qkv_b,
                                             bias_table, rel_idx, out);
        k_proj<<<(BWIN * NTOK) / 16, 192, 0, stream>>>(out, proj_w, proj_b);
    }
}

// Round 12
// 806.412 us; speedup vs baseline: 2.2968x; 1.0113x over previous
//
#include <hip/hip_runtime.h>

// WindowAttention (Swin-style), MI355X. Round 9.
// r8 post-mortem: cvt_pk cut VALU 41.5->34.3 but dur only -2.5%; FETCH
// unchanged 704MB (grid transpose no-op: consecutive blocks round-robin
// across XCDs -> 9 panel-sharing blocks on 9 different L2s). K1 is
// latency-bound at 23% occupancy, not VALU/HBM/MFMA-bound.
// Fixes:
//  - k_prep_x: X fp32 -> hi/lo bf16 frag blocks ONCE (LDS-transposed for
//    coalesced read AND write). K1 A-staging becomes global_load_lds like B:
//    inner loop = 8 gload16 + 16 ds_read_b128 + 48 MFMA, zero VALU (m97 form).
//  - bijective XCD swizzle (T1) for K1 (lid=(bid%8)*882+bid/8) and K3 (x294):
//    panel-sharing blocks land temporally adjacent on the SAME XCD -> X
//    re-reads hit the 4MB L2 instead of HBM.
// Tiers: FULL (+Xfrag 154MB) -> MID (r8 in-kernel split) -> fp32 fallback.

#define DIMC   384
#define NTOK   49
#define NHEAD  12
#define HD     32
#define NWIN   64
#define BWIN   2048
#define SCALE  0.17677669529663687f  // 1/sqrt(32)

#define SLOT     4704                // ushorts per (b,h): 3*49*32
#define NBQ      9
#define NBP      3
#define NRP      784                 // row panels of 128
#define FRAG_BLK 8192                // ushorts per (panel,kc): [2 hl][4 kq][128][8]

#define WS_SLOTS ((size_t)BWIN * NHEAD * SLOT)      // ushorts
#define WS_BFRAG ((size_t)NBQ * 12 * FRAG_BLK)
#define WS_PFRAG ((size_t)NBP * 12 * FRAG_BLK)
#define WS_XFRAG ((size_t)NRP * 12 * FRAG_BLK)
#define WS_COMB  ((size_t)NWIN * NHEAD * NTOK * 64) // floats
#define WS_NEED_MID  ((WS_SLOTS + WS_BFRAG + WS_PFRAG) * 2 + WS_COMB * 4)
#define WS_NEED_FULL (WS_NEED_MID + WS_XFRAG * 2)

typedef short bf16x8 __attribute__((ext_vector_type(8)));
typedef unsigned short u16x8 __attribute__((ext_vector_type(8)));
typedef unsigned u32x4 __attribute__((ext_vector_type(4)));
typedef float f32x4  __attribute__((ext_vector_type(4)));

__device__ __forceinline__ unsigned short f2bf(float f) {
    union { float f; unsigned u; } v; v.f = f;
    unsigned r = v.u + 0x7fffu + ((v.u >> 16) & 1u);   // RTN-even
    return (unsigned short)(r >> 16);
}
__device__ __forceinline__ float bf2f(unsigned short h) {
    union { unsigned u; float f; } v; v.u = ((unsigned)h) << 16;
    return v.f;
}
__device__ __forceinline__ void split2(float x, unsigned short& hi, unsigned short& lo) {
    hi = f2bf(x);
    lo = f2bf(x - bf2f(hi));
}
// packed bf16 convert (RTE, == RTN-even for normals): lo16=bf16(a), hi16=bf16(b)
__device__ __forceinline__ unsigned cvtpk(float a, float b) {
    unsigned r;
    asm("v_cvt_pk_bf16_f32 %0, %1, %2" : "=v"(r) : "v"(a), "v"(b));
    return r;
}
__device__ __forceinline__ unsigned lopk(float a, float b, unsigned h) {
    union { unsigned u; float f; } h0, h1;
    h0.u = h << 16; h1.u = h & 0xffff0000u;
    return cvtpk(a - h0.f, b - h1.f);
}
// 8 fp32 -> packed hi plane (4 u32) + lo plane (4 u32)
__device__ __forceinline__ void splitpk8(float4 a, float4 b, u32x4& h, u32x4& l) {
    h[0] = cvtpk(a.x, a.y); h[1] = cvtpk(a.z, a.w);
    h[2] = cvtpk(b.x, b.y); h[3] = cvtpk(b.z, b.w);
    l[0] = lopk(a.x, a.y, h[0]); l[1] = lopk(a.z, a.w, h[1]);
    l[2] = lopk(b.x, b.y, h[2]); l[3] = lopk(b.z, b.w, h[3]);
}
__device__ __forceinline__ float4 ld4(const float* p) {
    return *reinterpret_cast<const float4*>(p);
}
// async global->LDS, 16B/lane. LDS dest = wave-uniform base + lane*16.
__device__ __forceinline__ void gload16(const unsigned short* g, unsigned short* l) {
    __builtin_amdgcn_global_load_lds(
        (const __attribute__((address_space(1))) void*)g,
        (__attribute__((address_space(3))) void*)l, 16, 0, 0);
}

// ---------------------------------------------------------------------------
// K0a: pre-split a [384 x ncols] fp32 weight into hi/lo bf16 fragment blocks.
// ---------------------------------------------------------------------------
__global__ __launch_bounds__(256) void k_prep_w(
    const float* __restrict__ w, unsigned short* __restrict__ dst, int ncols)
{
    int f = blockIdx.x * 256 + threadIdx.x;
    if (f >= ncols * 48) return;
    int nb = f / 6144, rem = f - nb * 6144;     // 6144 = 12*4*128
    int kc = rem >> 9, rem2 = rem & 511;
    int kq = rem2 >> 7, rl = rem2 & 127;
    int n = nb * 128 + rl, k0 = kc * 32 + kq * 8;
    u16x8 h8, l8;
    #pragma unroll
    for (int e = 0; e < 8; ++e) {
        unsigned short hh, ll;
        split2(w[(size_t)(k0 + e) * ncols + n], hh, ll);
        h8[e] = hh; l8[e] = ll;
    }
    size_t base = ((size_t)(nb * 12 + kc) << 13) + (size_t)((kq << 7) + rl) * 8;
    *reinterpret_cast<u16x8*>(&dst[base])        = h8;
    *reinterpret_cast<u16x8*>(&dst[base + 4096]) = l8;
}

// ---------------------------------------------------------------------------
// K0c: pre-split X (100352x384 fp32) into hi/lo bf16 frag blocks, LDS-staged
// so global reads AND writes are coalesced. One block per (rp, kc):
// read 128x32 fp32 (rows of 128B), split via cvt_pk, write 16KB contiguous.
// ---------------------------------------------------------------------------
__global__ __launch_bounds__(256) void k_prep_x(
    const float* __restrict__ x, unsigned short* __restrict__ xf)
{
    __shared__ __align__(16) unsigned short H[4096], L[4096];
    const int bid = blockIdx.x, rp = bid / 12, kc = bid - rp * 12;
    const int t = threadIdx.x;
    const int row0 = t >> 3, c4 = t & 7;       // 8 lanes cover one row's 128B
    #pragma unroll
    for (int p = 0; p < 4; ++p) {
        int row = p * 32 + row0;
        float4 v = ld4(x + (size_t)(rp * 128 + row) * DIMC + kc * 32 + c4 * 4);
        unsigned h0 = cvtpk(v.x, v.y), h1 = cvtpk(v.z, v.w);
        unsigned l0 = lopk(v.x, v.y, h0), l1 = lopk(v.z, v.w, h1);
        int off = ((c4 >> 1) * 128 + row) * 8 + (c4 & 1) * 4;   // [kq][row][e]
        *reinterpret_cast<unsigned*>(&H[off])     = h0;
        *reinterpret_cast<unsigned*>(&H[off + 2]) = h1;
        *reinterpret_cast<unsigned*>(&L[off])     = l0;
        *reinterpret_cast<unsigned*>(&L[off + 2]) = l1;
    }
    __syncthreads();
    unsigned short* dst = xf + (size_t)bid * FRAG_BLK;
    #pragma unroll
    for (int p = 0; p < 4; ++p) {
        int o = p * 2048 + t * 8;
        u16x8 v = (p < 2) ? *reinterpret_cast<const u16x8*>(&H[o])
                          : *reinterpret_cast<const u16x8*>(&L[o - 4096]);
        *reinterpret_cast<u16x8*>(&dst[p * 2048 + t * 8]) = v;
    }
}

// ---------------------------------------------------------------------------
// K0b: comb[w*12+h][i(49)][j(64)] = mask[w][i][j] + bias_table[rel_idx[i][j]][h]
// for j<49, else -1e9 (padded cols vanish in softmax). 768 blocks.
// ---------------------------------------------------------------------------
__global__ __launch_bounds__(256) void k_prep_comb(
    const float* __restrict__ mask, const float* __restrict__ bias_table,
    const int* __restrict__ rel_idx, float* __restrict__ comb)
{
    int wh = blockIdx.x;            // w*12 + h
    int w = wh / NHEAD, h = wh - w * NHEAD;
    float* dst = comb + (size_t)wh * (NTOK * 64);
    for (int o = threadIdx.x; o < NTOK * 64; o += 256) {
        int i = o >> 6, j = o & 63;
        float v = -1e9f;
        if (j < NTOK) {
            int o2 = i * NTOK + j;
            v = mask[w * NTOK * NTOK + o2] + bias_table[rel_idx[o2] * NHEAD + h];
        }
        dst[o] = v;
    }
}

// ---------------------------------------------------------------------------
// K1-FULL: Y = X @ W + b, both operands pre-split -> pure gload16 staging,
// zero VALU in K-loop (m97 form). 1D grid 7056, bijective XCD swizzle:
// lid = (bid%8)*882 + bid/8; rp = lid/9, nb = lid%9 -> the 9 blocks sharing
// an X panel run adjacently on ONE XCD (L2-hit re-reads).
// ---------------------------------------------------------------------------
__global__ __launch_bounds__(256) void k_gemm_qkv_f(
    const unsigned short* __restrict__ Xfrag, const unsigned short* __restrict__ Bfrag,
    const float* __restrict__ qb, unsigned short* __restrict__ ws)
{
    __shared__ __align__(16) unsigned short Als[FRAG_BLK];
    __shared__ __align__(16) unsigned short Bls[FRAG_BLK];

    const int t = threadIdx.x;
    const int wave = t >> 6, l = t & 63, lj = l & 15, quad = l >> 4;
    const int wm = wave & 1, wn = wave >> 1;

    const int bid = blockIdx.x;
    const int lid = (bid & 7) * 882 + (bid >> 3);      // 7056/8 = 882
    const int rp = lid / 9, nb = lid - rp * 9;
    const int gm0 = rp * 128, gn0 = nb * 128;

    const unsigned short* Ag = Xfrag + (size_t)rp * 12 * FRAG_BLK;
    const unsigned short* Bg = Bfrag + (size_t)nb * 12 * FRAG_BLK;

    f32x4 acc[4][4];
    #pragma unroll
    for (int i = 0; i < 4; ++i)
        #pragma unroll
        for (int j = 0; j < 4; ++j) acc[i][j] = (f32x4)0.0f;

    for (int kc = 0; kc < 12; ++kc) {
        #pragma unroll
        for (int c = 0; c < 4; ++c) {
            int ch = wave * 4 + c;
            gload16(Ag + (size_t)kc * FRAG_BLK + ch * 512 + l * 8, &Als[ch * 512]);
            gload16(Bg + (size_t)kc * FRAG_BLK + ch * 512 + l * 8, &Bls[ch * 512]);
        }
        __syncthreads();

        bf16x8 ah[4], al[4], bh[4], bl[4];
        #pragma unroll
        for (int i = 0; i < 4; ++i) {
            int ra = (quad * 128 + wm * 64 + i * 16 + lj) * 8;
            ah[i] = *reinterpret_cast<const bf16x8*>(&Als[ra]);
            al[i] = *reinterpret_cast<const bf16x8*>(&Als[4096 + ra]);
            int rb = (quad * 128 + wn * 64 + i * 16 + lj) * 8;
            bh[i] = *reinterpret_cast<const bf16x8*>(&Bls[rb]);
            bl[i] = *reinterpret_cast<const bf16x8*>(&Bls[4096 + rb]);
        }
        #pragma unroll
        for (int tm = 0; tm < 4; ++tm)
            #pragma unroll
            for (int tn = 0; tn < 4; ++tn) {
                acc[tm][tn] = __builtin_amdgcn_mfma_f32_16x16x32_bf16(ah[tm], bh[tn], acc[tm][tn], 0, 0, 0);
                acc[tm][tn] = __builtin_amdgcn_mfma_f32_16x16x32_bf16(ah[tm], bl[tn], acc[tm][tn], 0, 0, 0);
                acc[tm][tn] = __builtin_amdgcn_mfma_f32_16x16x32_bf16(al[tm], bh[tn], acc[tm][tn], 0, 0, 0);
            }
        __syncthreads();
    }

    #pragma unroll
    for (int tn = 0; tn < 4; ++tn) {
        int col = gn0 + wn * 64 + tn * 16 + lj;          // 0..1151
        float bias = qb[col];
        int part = col / 384, rem = col - part * 384;
        int h = rem >> 5, d = rem & 31;
        #pragma unroll
        for (int tm = 0; tm < 4; ++tm) {
            #pragma unroll
            for (int rr = 0; rr < 4; ++rr) {
                int row = gm0 + wm * 64 + tm * 16 + quad * 4 + rr;
                int b = row / 49, n = row - b * 49;
                size_t off = ((size_t)(b * NHEAD + h) * 3 + part) * 1568 + n * HD + d;
                ws[off] = f2bf(acc[tm][tn][rr] + bias);
            }
        }
    }
}

// ---------------------------------------------------------------------------
// K1-MID (r8): in-kernel cvt_pk split of X. Grid (9,784).
// ---------------------------------------------------------------------------
__global__ __launch_bounds__(256) void k_gemm_qkv(
    const float* __restrict__ x, const unsigned short* __restrict__ Bfrag,
    const float* __restrict__ qb, unsigned short* __restrict__ ws)
{
    __shared__ __align__(16) unsigned short Als[FRAG_BLK];
    __shared__ __align__(16) unsigned short Bls[FRAG_BLK];

    const int t = threadIdx.x;
    const int wave = t >> 6, l = t & 63, lj = l & 15, quad = l >> 4;
    const int wm = wave & 1, wn = wave >> 1;
    const int gm0 = blockIdx.y * 128, gn0 = blockIdx.x * 128;

    const int fs0 = t, fs1 = t + 256;
    const float* xp0 = x + (size_t)(gm0 + (fs0 & 127)) * DIMC + (fs0 >> 7) * 8;
    const float* xp1 = x + (size_t)(gm0 + (fs1 & 127)) * DIMC + (fs1 >> 7) * 8;
    const unsigned short* Bg = Bfrag + (size_t)blockIdx.x * 12 * FRAG_BLK;

    f32x4 acc[4][4];
    #pragma unroll
    for (int i = 0; i < 4; ++i)
        #pragma unroll
        for (int j = 0; j < 4; ++j) acc[i][j] = (f32x4)0.0f;

    for (int kc = 0; kc < 12; ++kc) {
        #pragma unroll
        for (int c = 0; c < 4; ++c) {
            int ch = wave * 4 + c;
            gload16(Bg + (size_t)kc * FRAG_BLK + ch * 512 + l * 8, &Bls[ch * 512]);
        }
        {
            float4 x0 = ld4(xp0 + kc * 32), x1 = ld4(xp0 + kc * 32 + 4);
            u32x4 h, lo;
            splitpk8(x0, x1, h, lo);
            *reinterpret_cast<u32x4*>(&Als[fs0 * 8])        = h;
            *reinterpret_cast<u32x4*>(&Als[4096 + fs0 * 8]) = lo;
        }
        {
            float4 x0 = ld4(xp1 + kc * 32), x1 = ld4(xp1 + kc * 32 + 4);
            u32x4 h, lo;
            splitpk8(x0, x1, h, lo);
            *reinterpret_cast<u32x4*>(&Als[fs1 * 8])        = h;
            *reinterpret_cast<u32x4*>(&Als[4096 + fs1 * 8]) = lo;
        }
        __syncthreads();

        bf16x8 ah[4], al[4], bh[4], bl[4];
        #pragma unroll
        for (int i = 0; i < 4; ++i) {
            int ra = (quad * 128 + wm * 64 + i * 16 + lj) * 8;
            ah[i] = *reinterpret_cast<const bf16x8*>(&Als[ra]);
            al[i] = *reinterpret_cast<const bf16x8*>(&Als[4096 + ra]);
            int rb = (quad * 128 + wn * 64 + i * 16 + lj) * 8;
            bh[i] = *reinterpret_cast<const bf16x8*>(&Bls[rb]);
            bl[i] = *reinterpret_cast<const bf16x8*>(&Bls[4096 + rb]);
        }
        #pragma unroll
        for (int tm = 0; tm < 4; ++tm)
            #pragma unroll
            for (int tn = 0; tn < 4; ++tn) {
                acc[tm][tn] = __builtin_amdgcn_mfma_f32_16x16x32_bf16(ah[tm], bh[tn], acc[tm][tn], 0, 0, 0);
                acc[tm][tn] = __builtin_amdgcn_mfma_f32_16x16x32_bf16(ah[tm], bl[tn], acc[tm][tn], 0, 0, 0);
                acc[tm][tn] = __builtin_amdgcn_mfma_f32_16x16x32_bf16(al[tm], bh[tn], acc[tm][tn], 0, 0, 0);
            }
        __syncthreads();
    }

    #pragma unroll
    for (int tn = 0; tn < 4; ++tn) {
        int col = gn0 + wn * 64 + tn * 16 + lj;          // 0..1151
        float bias = qb[col];
        int part = col / 384, rem = col - part * 384;
        int h = rem >> 5, d = rem & 31;
        #pragma unroll
        for (int tm = 0; tm < 4; ++tm) {
            #pragma unroll
            for (int rr = 0; rr < 4; ++rr) {
                int row = gm0 + wm * 64 + tm * 16 + quad * 4 + rr;
                int b = row / 49, n = row - b * 49;
                size_t off = ((size_t)(b * NHEAD + h) * 3 + part) * 1568 + n * HD + d;
                ws[off] = f2bf(acc[tm][tn][rr] + bias);
            }
        }
    }
}

// ---------------------------------------------------------------------------
// K2: MFMA attention. Block = 128 (2 waves), each wave one (b,h).
// ---------------------------------------------------------------------------
__global__ __launch_bounds__(128) void k_attn_mfma(
    unsigned short* __restrict__ ws, const float* __restrict__ comb)
{
    __shared__ __align__(16) unsigned short Pimg[2][8192];  // hi plane | lo plane
    __shared__ __align__(16) unsigned short Vts[2][2048];   // V^T [32][64] swizzled

    const int t = threadIdx.x, wave = t >> 6, l = t & 63;
    const int lj = l & 15, quad = l >> 4;
    const int idx = blockIdx.x * 2 + wave;          // b*12 + h
    const int b = idx / NHEAD, h = idx - b * NHEAD;
    unsigned short* qp = ws + (size_t)idx * SLOT;
    const float* cb = comb + (size_t)((b & (NWIN - 1)) * NHEAD + h) * (NTOK * 64);
    unsigned short* pimg = Pimg[wave];
    unsigned short* vt   = Vts[wave];

    // zero Vt (padded cols j>=49 must be 0)
    #pragma unroll
    for (int it = 0; it < 4; ++it)
        *reinterpret_cast<u16x8*>(&vt[it * 512 + l * 8]) = (u16x8)0;

    // V chunk loads to regs: chunk c covers V[j = c>>2][d = (c&3)*8 .. +7]
    u16x8 vc[4];
    #pragma unroll
    for (int it = 0; it < 4; ++it) {
        int c = it * 64 + l;
        vc[it] = (c < 196)
            ? *reinterpret_cast<const u16x8*>(qp + 3136 + (c >> 2) * HD + (c & 3) * 8)
            : (u16x8)0;
    }

    // Q (A) and K (B) fragments straight from the slot (frag-order layout)
    bf16x8 aq[4], bk[4];
    #pragma unroll
    for (int mt = 0; mt < 4; ++mt) {
        int row = mt * 16 + lj;
        aq[mt] = (row < NTOK)
            ? *reinterpret_cast<const bf16x8*>(qp + row * HD + quad * 8) : (bf16x8)0;
        bk[mt] = (row < NTOK)
            ? *reinterpret_cast<const bf16x8*>(qp + 1568 + row * HD + quad * 8) : (bf16x8)0;
    }

    // QK^T: S[i][j], i = mt*16+quad*4+r, j = nt*16+lj
    f32x4 s[4][4];
    #pragma unroll
    for (int mt = 0; mt < 4; ++mt)
        #pragma unroll
        for (int nt = 0; nt < 4; ++nt)
            s[mt][nt] = __builtin_amdgcn_mfma_f32_16x16x32_bf16(aq[mt], bk[nt], (f32x4)0.0f, 0, 0, 0);

    // scale + bias/mask
    #pragma unroll
    for (int mt = 0; mt < 4; ++mt)
        #pragma unroll
        for (int r = 0; r < 4; ++r) {
            int i = mt * 16 + quad * 4 + r;
            #pragma unroll
            for (int nt = 0; nt < 4; ++nt) {
                float c = (i < NTOK) ? cb[i * 64 + nt * 16 + lj] : -1e9f;
                s[mt][nt][r] = fmaf(s[mt][nt][r], SCALE, c);
            }
        }

    __syncthreads();   // Vt zero visible block-wide

    // scatter V^T into LDS: vt[(d*64 + j) ^ ((d&7)<<3)]
    #pragma unroll
    for (int it = 0; it < 4; ++it) {
        int c = it * 64 + l;
        if (c < 196) {
            int j = c >> 2, dq = c & 3;
            #pragma unroll
            for (int e = 0; e < 8; ++e) {
                int d = dq * 8 + e;
                vt[(d * 64 + j) ^ ((d & 7) << 3)] = (unsigned short)vc[it][e];
            }
        }
    }

    // softmax per row (16 lanes share a row -> shfl_xor 1,2,4,8) + P hi/lo
    #pragma unroll
    for (int mt = 0; mt < 4; ++mt)
        #pragma unroll
        for (int r = 0; r < 4; ++r) {
            float m = fmaxf(fmaxf(s[mt][0][r], s[mt][1][r]),
                            fmaxf(s[mt][2][r], s[mt][3][r]));
            m = fmaxf(m, __shfl_xor(m, 1));
            m = fmaxf(m, __shfl_xor(m, 2));
            m = fmaxf(m, __shfl_xor(m, 4));
            m = fmaxf(m, __shfl_xor(m, 8));
            float e0 = __expf(s[mt][0][r] - m), e1 = __expf(s[mt][1][r] - m);
            float e2 = __expf(s[mt][2][r] - m), e3 = __expf(s[mt][3][r] - m);
            float sum = (e0 + e1) + (e2 + e3);
            sum += __shfl_xor(sum, 1);
            sum += __shfl_xor(sum, 2);
            sum += __shfl_xor(sum, 4);
            sum += __shfl_xor(sum, 8);
            float inv = 1.0f / sum;
            int i = mt * 16 + quad * 4 + r;
            int swz = (i & 7) << 3;
            float p0 = e0 * inv, p1 = e1 * inv, p2 = e2 * inv, p3 = e3 * inv;
            unsigned short hh, ll;
            split2(p0, hh, ll);
            pimg[(i * 64 +  0 + lj) ^ swz] = hh; pimg[4096 + ((i * 64 +  0 + lj) ^ swz)] = ll;
            split2(p1, hh, ll);
            pimg[(i * 64 + 16 + lj) ^ swz] = hh; pimg[4096 + ((i * 64 + 16 + lj) ^ swz)] = ll;
            split2(p2, hh, ll);
            pimg[(i * 64 + 32 + lj) ^ swz] = hh; pimg[4096 + ((i * 64 + 32 + lj) ^ swz)] = ll;
            split2(p3, hh, ll);
            pimg[(i * 64 + 48 + lj) ^ swz] = hh; pimg[4096 + ((i * 64 + 48 + lj) ^ swz)] = ll;
        }

    __syncthreads();   // P and V^T scatters complete

    // PV: O[i][d] = sum_j P[i][j] V[j][d]; A = P (hi+lo), B = V^T frags
    f32x4 o[4][2];
    #pragma unroll
    for (int mt = 0; mt < 4; ++mt) { o[mt][0] = (f32x4)0.0f; o[mt][1] = (f32x4)0.0f; }
    #pragma unroll
    for (int ks = 0; ks < 2; ++ks) {
        bf16x8 bv[2];
        #pragma unroll
        for (int nt = 0; nt < 2; ++nt) {
            int d = nt * 16 + lj;
            bv[nt] = *reinterpret_cast<const bf16x8*>(
                &vt[(d * 64 + ks * 32 + quad * 8) ^ ((d & 7) << 3)]);
        }
        #pragma unroll
        for (int mt = 0; mt < 4; ++mt) {
            int i = mt * 16 + lj;
            int fo = (i * 64 + ks * 32 + quad * 8) ^ ((i & 7) << 3);
            bf16x8 ph = *reinterpret_cast<const bf16x8*>(&pimg[fo]);
            bf16x8 pl = *reinterpret_cast<const bf16x8*>(&pimg[4096 + fo]);
            #pragma unroll
            for (int nt = 0; nt < 2; ++nt) {
                o[mt][nt] = __builtin_amdgcn_mfma_f32_16x16x32_bf16(ph, bv[nt], o[mt][nt], 0, 0, 0);
                o[mt][nt] = __builtin_amdgcn_mfma_f32_16x16x32_bf16(pl, bv[nt], o[mt][nt], 0, 0, 0);
            }
        }
    }

    // write O (bf16) over own q slot
    #pragma unroll
    for (int mt = 0; mt < 4; ++mt)
        #pragma unroll
        for (int r = 0; r < 4; ++r) {
            int i = mt * 16 + quad * 4 + r;
            if (i < NTOK) {
                qp[i * HD + lj]      = f2bf(o[mt][0][r]);
                qp[i * HD + 16 + lj] = f2bf(o[mt][1][r]);
            }
        }
}

// ---------------------------------------------------------------------------
// K3: out = Y2(100352x384 bf16 slots) @ proj_w + b, fp32 out. 1D grid 2352,
// bijective XCD swizzle (x294): panel-sharing blocks adjacent on one XCD.
// ---------------------------------------------------------------------------
__global__ __launch_bounds__(256) void k_gemm_proj(
    const unsigned short* __restrict__ ws, const unsigned short* __restrict__ Pfrag,
    const float* __restrict__ pbias, float* __restrict__ out)
{
    __shared__ __align__(16) unsigned short Als[4096];      // [4 kq][128][8], 8KB
    __shared__ __align__(16) unsigned short Bls[FRAG_BLK];  // hi/lo, 16KB

    const int t = threadIdx.x;
    const int wave = t >> 6, l = t & 63, lj = l & 15, quad = l >> 4;
    const int wm = wave & 1, wn = wave >> 1;

    const int bid = blockIdx.x;
    const int lid = (bid & 7) * 294 + (bid >> 3);      // 2352/8 = 294
    const int rp = lid / 3, nb = lid - rp * 3;
    const int gm0 = rp * 128, gn0 = nb * 128;

    const int ch0 = wave * 2, ch1 = wave * 2 + 1;
    size_t abase0, abase1;
    {
        int fs = ch0 * 64 + l;
        int kq = fs >> 7, rl = fs & 127, row = gm0 + rl;
        int b = row / 49, n = row - b * 49;
        abase0 = (size_t)(b * NHEAD) * SLOT + n * HD + kq * 8;
    }
    {
        int fs = ch1 * 64 + l;
        int kq = fs >> 7, rl = fs & 127, row = gm0 + rl;
        int b = row / 49, n = row - b * 49;
        abase1 = (size_t)(b * NHEAD) * SLOT + n * HD + kq * 8;
    }
    const unsigned short* Bg = Pfrag + (size_t)nb * 12 * FRAG_BLK;

    f32x4 acc[4][4];
    #pragma unroll
    for (int i = 0; i < 4; ++i)
        #pragma unroll
        for (int j = 0; j < 4; ++j) acc[i][j] = (f32x4)0.0f;

    for (int kc = 0; kc < 12; ++kc) {       // kc == head index
        #pragma unroll
        for (int c = 0; c < 4; ++c) {
            int ch = wave * 4 + c;
            gload16(Bg + (size_t)kc * FRAG_BLK + ch * 512 + l * 8, &Bls[ch * 512]);
        }
        gload16(ws + abase0 + (size_t)kc * SLOT, &Als[ch0 * 512]);
        gload16(ws + abase1 + (size_t)kc * SLOT, &Als[ch1 * 512]);
        __syncthreads();

        bf16x8 a[4], bh[4], bl[4];
        #pragma unroll
        for (int i = 0; i < 4; ++i) {
            a[i] = *reinterpret_cast<const bf16x8*>(&Als[(quad * 128 + wm * 64 + i * 16 + lj) * 8]);
            int rb = (quad * 128 + wn * 64 + i * 16 + lj) * 8;
            bh[i] = *reinterpret_cast<const bf16x8*>(&Bls[rb]);
            bl[i] = *reinterpret_cast<const bf16x8*>(&Bls[4096 + rb]);
        }
        #pragma unroll
        for (int tm = 0; tm < 4; ++tm)
            #pragma unroll
            for (int tn = 0; tn < 4; ++tn) {
                acc[tm][tn] = __builtin_amdgcn_mfma_f32_16x16x32_bf16(a[tm], bh[tn], acc[tm][tn], 0, 0, 0);
                acc[tm][tn] = __builtin_amdgcn_mfma_f32_16x16x32_bf16(a[tm], bl[tn], acc[tm][tn], 0, 0, 0);
            }
        __syncthreads();
    }

    #pragma unroll
    for (int tn = 0; tn < 4; ++tn) {
        int col = gn0 + wn * 64 + tn * 16 + lj;
        float bias = pbias[col];
        #pragma unroll
        for (int tm = 0; tm < 4; ++tm)
            #pragma unroll
            for (int rr = 0; rr < 4; ++rr) {
                int row = gm0 + wm * 64 + tm * 16 + quad * 4 + rr;
                out[(size_t)row * DIMC + col] = acc[tm][tn][rr] + bias;
            }
    }
}

// ============================ fp32 fallback (round 0) =======================
__global__ __launch_bounds__(192) void k_qkv_attn(
    const float* __restrict__ x, const float* __restrict__ mask,
    const float* __restrict__ qkv_w, const float* __restrict__ qkv_b,
    const float* __restrict__ bias_table, const int* __restrict__ rel_idx,
    float* __restrict__ out)
{
    __shared__ __align__(16) float xs_t[64 * 68];
    __shared__ __align__(16) float qs[NTOK * HD];
    __shared__ __align__(16) float ks_[NTOK * HD];
    __shared__ __align__(16) float vs[NTOK * HD];
    __shared__ __align__(16) union { float w[64 * 96]; float s[NTOK * 56]; } u;

    const int t = threadIdx.x, b = blockIdx.x;
    const int tx = t % 12, ty = t / 12;
    const float* xb = x + (size_t)b * NTOK * DIMC;
    const int mbase = (b % NWIN) * NTOK * NTOK;

    for (int h = 0; h < NHEAD; ++h) {
        float acc[4][8];
        #pragma unroll
        for (int r = 0; r < 4; ++r)
            #pragma unroll
            for (int cc = 0; cc < 8; ++cc) acc[r][cc] = 0.0f;
        for (int c0 = 0; c0 < DIMC; c0 += 64) {
            for (int idx = t; idx < NTOK * 64; idx += 192) {
                int i = idx >> 6, kk2 = idx & 63;
                xs_t[kk2 * 68 + i] = xb[i * DIMC + c0 + kk2];
            }
            for (int idx = t; idx < 64 * 96; idx += 192) {
                int kk2 = idx / 96, c = idx % 96;
                int col = (c >> 5) * DIMC + h * HD + (c & 31);
                u.w[kk2 * 96 + c] = qkv_w[(size_t)(c0 + kk2) * (3 * DIMC) + col];
            }
            __syncthreads();
            #pragma unroll 8
            for (int kk2 = 0; kk2 < 64; ++kk2) {
                const float4 xv = ld4(&xs_t[kk2 * 68 + ty * 4]);
                const float4 w0 = ld4(&u.w[kk2 * 96 + tx * 8]);
                const float4 w1 = ld4(&u.w[kk2 * 96 + tx * 8 + 4]);
                const float xr[4] = {xv.x, xv.y, xv.z, xv.w};
                const float wc[8] = {w0.x, w0.y, w0.z, w0.w, w1.x, w1.y, w1.z, w1.w};
                #pragma unroll
                for (int r = 0; r < 4; ++r)
                    #pragma unroll
                    for (int cc = 0; cc < 8; ++cc)
                        acc[r][cc] = fmaf(xr[r], wc[cc], acc[r][cc]);
            }
            __syncthreads();
        }
        {
            const int part = tx >> 2, cbase = (tx & 3) * 8;
            float* dst = (part == 0) ? qs : (part == 1) ? ks_ : vs;
            #pragma unroll
            for (int r = 0; r < 4; ++r) {
                int i = ty * 4 + r;
                if (i < NTOK)
                    #pragma unroll
                    for (int cc = 0; cc < 8; ++cc) {
                        int c5 = cbase + cc;
                        dst[i * HD + c5] = acc[r][cc] + qkv_b[part * DIMC + h * HD + c5];
                    }
            }
        }
        __syncthreads();
        for (int o = t; o < NTOK * NTOK; o += 192) {
            int i = o / 49, j = o % 49;
            float4 a4 = {0.f, 0.f, 0.f, 0.f};
            #pragma unroll
            for (int seg = 0; seg < 8; ++seg) {
                float4 q4 = ld4(&qs[i * HD + seg * 4]);
                float4 k4 = ld4(&ks_[j * HD + seg * 4]);
                a4.x = fmaf(q4.x, k4.x, a4.x); a4.y = fmaf(q4.y, k4.y, a4.y);
                a4.z = fmaf(q4.z, k4.z, a4.z); a4.w = fmaf(q4.w, k4.w, a4.w);
            }
            u.s[i * 56 + j] = (a4.x + a4.y + a4.z + a4.w) * SCALE
                            + bias_table[rel_idx[o] * NHEAD + h] + mask[mbase + o];
        }
        __syncthreads();
        if (t < NTOK) {
            float* row = &u.s[t * 56];
            float m = row[0];
            for (int j = 1; j < NTOK; ++j) m = fmaxf(m, row[j]);
            float ssum = 0.f;
            for (int j = 0; j < NTOK; ++j) { float e = __expf(row[j] - m); row[j] = e; ssum += e; }
            float inv = 1.0f / ssum;
            for (int j = 0; j < NTOK; ++j) row[j] *= inv;
        }
        __syncthreads();
        for (int o = t; o < NTOK * 8; o += 192) {
            int i = o >> 3, dg = o & 7;
            float4 a = {0.f, 0.f, 0.f, 0.f};
            for (int j = 0; j < NTOK; ++j) {
                float sj = u.s[i * 56 + j];
                float4 v4 = ld4(&vs[j * HD + dg * 4]);
                a.x = fmaf(sj, v4.x, a.x); a.y = fmaf(sj, v4.y, a.y);
                a.z = fmaf(sj, v4.z, a.z); a.w = fmaf(sj, v4.w, a.w);
            }
            *reinterpret_cast<float4*>(&out[(size_t)(b * NTOK + i) * DIMC + h * HD + dg * 4]) = a;
        }
        __syncthreads();
    }
}

__global__ __launch_bounds__(192) void k_proj(
    float* __restrict__ io, const float* __restrict__ proj_w,
    const float* __restrict__ proj_b)
{
    __shared__ __align__(16) float ys_t[DIMC * 20];
    __shared__ __align__(16) float wch[16 * DIMC];
    const int t = threadIdx.x, row0 = blockIdx.x * 16;
    const int tx = t % 48, ty = t / 48;
    for (int idx = t; idx < 16 * DIMC; idx += 192) {
        int i = idx / DIMC, k = idx % DIMC;
        ys_t[k * 20 + i] = io[(size_t)(row0 + i) * DIMC + k];
    }
    float acc[4][8];
    #pragma unroll
    for (int r = 0; r < 4; ++r)
        #pragma unroll
        for (int cc = 0; cc < 8; ++cc) acc[r][cc] = 0.0f;
    for (int k0 = 0; k0 < DIMC; k0 += 16) {
        for (int idx = t; idx < 16 * DIMC; idx += 192) {
            int kk2 = idx / DIMC, c = idx % DIMC;
            wch[kk2 * DIMC + c] = proj_w[(size_t)(k0 + kk2) * DIMC + c];
        }
        __syncthreads();
        #pragma unroll
        for (int kk2 = 0; kk2 < 16; ++kk2) {
            const float4 xv = ld4(&ys_t[(k0 + kk2) * 20 + ty * 4]);
            const float4 w0 = ld4(&wch[kk2 * DIMC + tx * 8]);
            const float4 w1 = ld4(&wch[kk2 * DIMC + tx * 8 + 4]);
            const float xr[4] = {xv.x, xv.y, xv.z, xv.w};
            const float wc[8] = {w0.x, w0.y, w0.z, w0.w, w1.x, w1.y, w1.z, w1.w};
            #pragma unroll
            for (int r = 0; r < 4; ++r)
                #pragma unroll
                for (int cc = 0; cc < 8; ++cc)
                    acc[r][cc] = fmaf(xr[r], wc[cc], acc[r][cc]);
        }
        __syncthreads();
    }
    #pragma unroll
    for (int r = 0; r < 4; ++r) {
        int i = ty * 4 + r;
        float* dst = &io[(size_t)(row0 + i) * DIMC + tx * 8];
        #pragma unroll
        for (int cc = 0; cc < 8; ++cc) dst[cc] = acc[r][cc] + proj_b[tx * 8 + cc];
    }
}

extern "C" void kernel_launch(void* const* d_in, const int* in_sizes, int n_in,
                              void* d_out, int out_size, void* d_ws, size_t ws_size,
                              hipStream_t stream) {
    const float* x          = (const float*)d_in[0];
    const float* mask       = (const float*)d_in[1];
    const float* qkv_w      = (const float*)d_in[2];
    const float* qkv_b      = (const float*)d_in[3];
    const float* proj_w     = (const float*)d_in[4];
    const float* proj_b     = (const float*)d_in[5];
    const float* bias_table = (const float*)d_in[6];
    const int*   rel_idx    = (const int*)d_in[7];
    float* out = (float*)d_out;

    if (ws_size >= WS_NEED_MID) {
        unsigned short* ws = (unsigned short*)d_ws;
        unsigned short* Bf = ws + WS_SLOTS;
        unsigned short* Pf = Bf + WS_BFRAG;
        float* combf = (float*)(Pf + WS_PFRAG);
        unsigned short* Xf = (unsigned short*)(combf + WS_COMB);
        k_prep_w<<<216, 256, 0, stream>>>(qkv_w, Bf, 3 * DIMC);   // 55296 frags
        k_prep_w<<<72, 256, 0, stream>>>(proj_w, Pf, DIMC);       // 18432 frags
        k_prep_comb<<<NWIN * NHEAD, 256, 0, stream>>>(mask, bias_table, rel_idx, combf);
        if (ws_size >= WS_NEED_FULL) {
            k_prep_x<<<NRP * 12, 256, 0, stream>>>(x, Xf);
            k_gemm_qkv_f<<<NRP * NBQ, 256, 0, stream>>>(Xf, Bf, qkv_b, ws);
        } else {
            dim3 g1(NBQ, NRP);
            k_gemm_qkv<<<g1, 256, 0, stream>>>(x, Bf, qkv_b, ws);
        }
        k_attn_mfma<<<(BWIN * NHEAD) / 2, 128, 0, stream>>>(ws, combf);
        k_gemm_proj<<<NRP * NBP, 256, 0, stream>>>(ws, Pf, proj_b, out);
    } else {
        k_qkv_attn<<<BWIN, 192, 0, stream>>>(x, mask, qkv_w, qkv_b,
                                             bias_table, rel_idx, out);
        k_proj<<<(BWIN * NTOK) / 16, 192, 0, stream>>>(out, proj_w, proj_b);
    }
}